// Round 9
// baseline (507.134 us; speedup 1.0000x reference)
//
#include <hip/hip_runtime.h>
#include <hip/hip_bf16.h>
#include <math.h>

// Problem dims
#define N_NODES 20000
#define S_NE    16
#define E_EDGES 160000
#define NMP     2
#define H_HEADS 4
#define O_DIM   64
#define D_FEAT  64
#define E_DIMC  32
#define PREP    128
#define NCLS    8
#define B_TR    4096
#define D1      256           // H*O
#define NSLOT   (B_TR * S_NE) // 65536

// LDS row pads for fused fallback
#define LDA0    132
#define LDA1    260
// LDS ned plane pad (u16 units): 256+8 -> row stride 528B, bank-balanced b128
#define NPAD    264

typedef __hip_bfloat16 bf16;
typedef unsigned short u16;
typedef __attribute__((ext_vector_type(8))) short s8v;   // 8 bf16 (4 VGPRs)
typedef __attribute__((ext_vector_type(4))) float f4v;   // MFMA acc

template <typename T>
__device__ __forceinline__ float ldv(const void* p, size_t i) {
    if constexpr (sizeof(T) == 4) return ((const float*)p)[i];
    else return __bfloat162float(((const bf16*)p)[i]);
}
template <typename T>
__device__ __forceinline__ float4 ld4(const void* p, size_t i) {
    if constexpr (sizeof(T) == 4) {
        return *(const float4*)((const float*)p + i);
    } else {
        float4 r;
        r.x = ldv<T>(p, i); r.y = ldv<T>(p, i + 1);
        r.z = ldv<T>(p, i + 2); r.w = ldv<T>(p, i + 3);
        return r;
    }
}
template <typename T>
__device__ __forceinline__ void stv(void* p, size_t i, float v) {
    if constexpr (sizeof(T) == 4) ((float*)p)[i] = v;
    else ((bf16*)p)[i] = __float2bfloat16(v);
}
template <typename T>
__device__ __forceinline__ bool active(const int* flag) {
    return *flag == (sizeof(T) == 4 ? 1 : 0);
}

__device__ __forceinline__ u16 f2bf(float x) {
    bf16 h = __float2bfloat16(x);
    return *reinterpret_cast<u16*>(&h);
}
__device__ __forceinline__ float bf2f(u16 u) {
    bf16 h; *reinterpret_cast<u16*>(&h) = u;
    return __bfloat162float(h);
}
// split-bf16: x ~= hi + lo, product error ~2^-17 relative
__device__ __forceinline__ void splitbf(float x, u16& h, u16& l) {
    h = f2bf(x);
    l = f2bf(x - bf2f(h));
}

__device__ __forceinline__ float wave_sum(float v) {
    #pragma unroll
    for (int off = 32; off > 0; off >>= 1) v += __shfl_xor(v, off, 64);
    return v;
}
__device__ __forceinline__ float og_sum(float v) {
    v += __shfl_xor(v, 4, 64);  v += __shfl_xor(v, 8, 64);
    v += __shfl_xor(v, 16, 64); v += __shfl_xor(v, 32, 64);
    return v;
}
// sum within 16-lane group (lanes sharing lane>>4)
__device__ __forceinline__ float grp16_sum(float v) {
    v += __shfl_xor(v, 1, 64); v += __shfl_xor(v, 2, 64);
    v += __shfl_xor(v, 4, 64); v += __shfl_xor(v, 8, 64);
    return v;
}
__device__ __forceinline__ float mg_sum(float v) {
    v += __shfl_xor(v, 1, 64); v += __shfl_xor(v, 2, 64); return v;
}
__device__ __forceinline__ float mg_max(float v) {
    v = fmaxf(v, __shfl_xor(v, 1, 64)); v = fmaxf(v, __shfl_xor(v, 2, 64)); return v;
}
__device__ __forceinline__ float eluf(float x) { return x > 0.f ? x : expf(x) - 1.f; }
__device__ __forceinline__ float4 elu4(float4 v) {
    v.x = eluf(v.x); v.y = eluf(v.y); v.z = eluf(v.z); v.w = eluf(v.w); return v;
}

#define FMA4C(acc, s, b) do { (acc).x += (s)*(b).x; (acc).y += (s)*(b).y; \
                              (acc).z += (s)*(b).z; (acc).w += (s)*(b).w; } while (0)
#define ZERO4(v) do { (v).x = 0.f; (v).y = 0.f; (v).z = 0.f; (v).w = 0.f; } while (0)

// ---------------------------------------------------------------------------
// Dtype detector (R3-verified): flag=1 => fp32 buffers. flag at ws[0].
__global__ void k_detect(const unsigned* __restrict__ w, int* __restrict__ flag) {
    int t = threadIdx.x;
    int bad = 0;
    for (int i = t; i < 512; i += 64) {
        float v = __uint_as_float((w[i] & 0xffffu) << 16);
        if (!(fabsf(v) < 64.f)) bad++;
    }
    #pragma unroll
    for (int off = 32; off > 0; off >>= 1) bad += __shfl_xor(bad, off, 64);
    if (t == 0) *flag = (bad > 32) ? 1 : 0;
}

// ---------------------------------------------------------------------------
// Parallel precombined weights (one thread per output element, 98304 total):
//  c0: Wqe planes [mp][n=256][k=32] = (epw @ ewq)^T hi/lo     (MFMA B operand)
//  c1: Wk0 planes [mp][n=256][k=32] = (epw @ nwk0)^T hi/lo
//  c2: Wkn fp32 [mp][64][256] = Wp1 @ ewk                     (fp32 GEMM B)
//  c3: Wq0 fp32 [mp][64][256] = Wp0 @ nwq0
template <typename T>
__device__ void precomb2_body(const void* epw, const void* ewq, const void* nwk0,
                              const void* Wp1, const void* ewk,
                              const void* Wp0, const void* nwq0,
                              float* wkn, float* wq0,
                              u16* qeh, u16* qel, u16* k0h, u16* k0l) {
    int idx = blockIdx.x * 256 + threadIdx.x;
    if (idx >= 98304) return;
    int combo, rem;
    if (idx < 16384)      { combo = 0; rem = idx; }
    else if (idx < 32768) { combo = 1; rem = idx - 16384; }
    else if (idx < 65536) { combo = 2; rem = idx - 32768; }
    else                  { combo = 3; rem = idx - 65536; }
    int mp, r, n;
    if (combo < 2) { mp = rem >> 13; r = (rem >> 8) & 31; n = rem & 255; }
    else           { mp = rem >> 14; r = (rem >> 8) & 63; n = rem & 255; }
    int h = n >> 6, o = n & 63;
    const void* Aw; const void* Bw; size_t aoff;
    size_t boff = (size_t)mp * H_HEADS * PREP * O_DIM + (size_t)h * PREP * O_DIM + o;
    switch (combo) {
        case 0: Aw = epw; Bw = ewq;  aoff = (size_t)mp * E_DIMC * PREP + (size_t)r * PREP; break;
        case 1: Aw = epw; Bw = nwk0; aoff = (size_t)mp * E_DIMC * PREP + (size_t)r * PREP; break;
        case 2: Aw = Wp1; Bw = ewk;  aoff = (size_t)r * PREP; break;
        default:Aw = Wp0; Bw = nwq0; aoff = (size_t)r * PREP; break;
    }
    float acc = 0.f;
    #pragma unroll 4
    for (int p = 0; p < PREP; ++p)
        acc += ldv<T>(Aw, aoff + p) * ldv<T>(Bw, boff + (size_t)p * O_DIM);
    if (combo < 2) {
        u16 hh, ll; splitbf(acc, hh, ll);
        size_t dst = (size_t)mp * (256 * 32) + (size_t)n * 32 + r;
        if (combo == 0) { qeh[dst] = hh; qel[dst] = ll; }
        else            { k0h[dst] = hh; k0l[dst] = ll; }
    } else if (combo == 2) {
        wkn[(size_t)mp * 64 * D1 + (size_t)r * D1 + n] = acc;
    } else {
        wq0[(size_t)mp * 64 * D1 + (size_t)r * D1 + n] = acc;
    }
}
__global__ void k_precomb2(const void* epw, const void* ewq, const void* nwk0,
                           const void* Wp1, const void* ewk,
                           const void* Wp0, const void* nwq0,
                           float* wkn, float* wq0,
                           u16* qeh, u16* qel, u16* k0h, u16* k0l,
                           const int* flag) {
    if (*flag == 1) precomb2_body<float>(epw, ewq, nwk0, Wp1, ewk, Wp0, nwq0, wkn, wq0, qeh, qel, k0h, k0l);
    else            precomb2_body<bf16 >(epw, ewq, nwk0, Wp1, ewk, Wp0, nwq0, wkn, wq0, qeh, qel, k0h, k0l);
}

// edge_emb -> hi/lo bf16 planes [NMP][E][32] (coalesced)
template <typename T>
__device__ void embsplit_body(const void* emb, u16* eh, u16* el) {
    size_t idx = (size_t)blockIdx.x * 256 + threadIdx.x;
    if (idx >= (size_t)NMP * E_EDGES * E_DIMC) return;
    float v = ldv<T>(emb, idx);
    u16 hh, ll; splitbf(v, hh, ll);
    eh[idx] = hh; el[idx] = ll;
}
__global__ void k_embsplit(const void* emb, u16* eh, u16* el, const int* flag) {
    if (*flag == 1) embsplit_body<float>(emb, eh, el);
    else            embsplit_body<bf16 >(emb, eh, el);
}

// Transposed hi/lo planes of nwk1/nwq1: Bt[mp][n=256][k=256]
template <typename T>
__device__ void wt1_body(const void* wk1, const void* wq1,
                         u16* kth, u16* ktl, u16* qth, u16* qtl) {
    int idx = blockIdx.x * 256 + threadIdx.x;   // 0..262143
    int k = idx & 255, n = (idx >> 8) & 255;
    int wsel = (idx >> 16) & 1, mp = idx >> 17;
    size_t src = (size_t)mp * (H_HEADS * D1 * O_DIM) + (size_t)(n >> 6) * (D1 * O_DIM)
               + (size_t)k * O_DIM + (n & 63);
    float v = ldv<T>(wsel ? wq1 : wk1, src);
    u16 h, l; splitbf(v, h, l);
    size_t dst = (size_t)mp * 65536 + (size_t)n * 256 + k;
    if (wsel) { qth[dst] = h; qtl[dst] = l; }
    else      { kth[dst] = h; ktl[dst] = l; }
}
__global__ void k_wt1(const void* wk1, const void* wq1,
                      u16* kth, u16* ktl, u16* qth, u16* qtl, const int* flag) {
    if (*flag == 1) wt1_body<float>(wk1, wq1, kth, ktl, qth, qtl);
    else            wt1_body<bf16 >(wk1, wq1, kth, ktl, qth, qtl);
}

// Transposed hi/lo planes of Wg[512][128] -> Wgt[n=128][k=512]
template <typename T>
__device__ void wgt_body(const void* Wg, u16* gh, u16* gl) {
    int idx = blockIdx.x * 256 + threadIdx.x;   // 0..65535
    int n = idx >> 9, k = idx & 511;
    float v = ldv<T>(Wg, (size_t)k * PREP + n);
    u16 h, l; splitbf(v, h, l);
    gh[(size_t)n * 512 + k] = h;
    gl[(size_t)n * 512 + k] = l;
}
__global__ void k_wgt(const void* Wg, u16* gh, u16* gl, const int* flag) {
    if (*flag == 1) wgt_body<float>(Wg, gh, gl);
    else            wgt_body<bf16 >(Wg, gh, gl);
}

// ---------------------------------------------------------------------------
// fp32 register-tiled GEMM (R6-verified), mp-batched via blockIdx.z strides.
template <typename TA, typename TB>
__device__ void gemm_body(const void* A, size_t aOff, const int* Aidx, int strideA,
                          const float* B, int sH, int sD,
                          float* C, int ldC, int M, int K) {
    int bm = blockIdx.x * 64;
    int h  = blockIdx.y;
    int t  = threadIdx.x;
    int tx = t & 15, ty = t >> 4;

    __shared__ float As[32][68];
    __shared__ float Bs[32][68];

    float acc[4][4] = {{0.f}};
    int arow = t >> 3, kq = (t & 7) * 4;
    int brow = t >> 4, nq = (t & 15) * 4;

    for (int k0 = 0; k0 < K; k0 += 32) {
        #pragma unroll
        for (int c = 0; c < 2; ++c) {
            int rm = arow + 32 * c;
            int gr = bm + rm;
            gr = (gr < M) ? gr : 0;
            size_t row = Aidx ? (size_t)Aidx[gr] : (size_t)gr;
            float4 a = ld4<TA>(A, aOff + row * strideA + k0 + kq);
            As[kq + 0][rm] = a.x; As[kq + 1][rm] = a.y;
            As[kq + 2][rm] = a.z; As[kq + 3][rm] = a.w;
        }
        #pragma unroll
        for (int c = 0; c < 2; ++c) {
            int rk = brow + 16 * c;
            float4 b = ld4<float>(B, (size_t)h * sH + (size_t)(k0 + rk) * sD + nq);
            *(float4*)&Bs[rk][nq] = b;
        }
        __syncthreads();
        #pragma unroll
        for (int kk = 0; kk < 32; ++kk) {
            float4 av = *(const float4*)&As[kk][ty * 4];
            float4 bv = *(const float4*)&Bs[kk][tx * 4];
            float am[4] = {av.x, av.y, av.z, av.w};
            #pragma unroll
            for (int i = 0; i < 4; ++i) {
                acc[i][0] += am[i] * bv.x; acc[i][1] += am[i] * bv.y;
                acc[i][2] += am[i] * bv.z; acc[i][3] += am[i] * bv.w;
            }
        }
        __syncthreads();
    }
    #pragma unroll
    for (int i = 0; i < 4; ++i) {
        int m = bm + ty * 4 + i;
        if (m < M) {
            float4 st; st.x = acc[i][0]; st.y = acc[i][1];
            st.z = acc[i][2]; st.w = acc[i][3];
            *(float4*)&C[(size_t)m * ldC + h * 64 + tx * 4] = st;
        }
    }
}
__global__ __launch_bounds__(256) void k_gemm_rf(
        const void* A, size_t aOff, const int* Aidx, int strideA,
        const float* B, size_t bStride, int sH, int sD,
        float* C, size_t cStride, int ldC, int M, int K,
        const int* flag) {
    const float* Bz = B + (size_t)blockIdx.z * bStride;
    float* Cz = C + (size_t)blockIdx.z * cStride;
    if (*flag == 1) gemm_body<float, float>(A, aOff, Aidx, strideA, Bz, sH, sD, Cz, ldC, M, K);
    else            gemm_body<bf16,  float>(A, aOff, Aidx, strideA, Bz, sH, sD, Cz, ldC, M, K);
}

// ---------------------------------------------------------------------------
// Shared split-bf16 MFMA mainloop (R7-verified structure).
template <int K, bool G>
__device__ __forceinline__ void mfma_core(
        const u16* __restrict__ Ah, const u16* __restrict__ Al,
        const int* __restrict__ rows,
        const u16* __restrict__ Bh, const u16* __restrict__ Bl,
        int rbase, int bn, int lane, f4v acc[4][4]) {
    int fr = lane & 15;
    int kq = (lane >> 4) * 8;
    #pragma unroll
    for (int i = 0; i < 4; ++i)
        #pragma unroll
        for (int j = 0; j < 4; ++j) acc[i][j] = f4v{0.f, 0.f, 0.f, 0.f};
    #pragma unroll 2
    for (int k0 = 0; k0 < K; k0 += 32) {
        s8v ah[4], al[4], bh[4], bl[4];
        #pragma unroll
        for (int i = 0; i < 4; ++i) {
            size_t arow;
            if constexpr (G) arow = (size_t)rows[rbase + i * 16 + fr];
            else             arow = (size_t)(rbase + i * 16 + fr);
            size_t ao = arow * K + k0 + kq;
            ah[i] = *(const s8v*)(Ah + ao);
            al[i] = *(const s8v*)(Al + ao);
            size_t bo = (size_t)(bn + i * 16 + fr) * K + k0 + kq;
            bh[i] = *(const s8v*)(Bh + bo);
            bl[i] = *(const s8v*)(Bl + bo);
        }
        #pragma unroll
        for (int i = 0; i < 4; ++i)
            #pragma unroll
            for (int j = 0; j < 4; ++j) {
                acc[i][j] = __builtin_amdgcn_mfma_f32_16x16x32_bf16(al[i], bh[j], acc[i][j], 0, 0, 0);
                acc[i][j] = __builtin_amdgcn_mfma_f32_16x16x32_bf16(ah[i], bl[j], acc[i][j], 0, 0, 0);
                acc[i][j] = __builtin_amdgcn_mfma_f32_16x16x32_bf16(ah[i], bh[j], acc[i][j], 0, 0, 0);
            }
    }
}

// Plain-store MFMA GEMM (gate): C = A @ B^T-planes.
template <int K>
__global__ __launch_bounds__(256) void k_mfma(
        const u16* __restrict__ Ah, const u16* __restrict__ Al,
        const u16* __restrict__ Bh, const u16* __restrict__ Bl,
        float* __restrict__ C, int ldC) {
    int w = threadIdx.x >> 6, lane = threadIdx.x & 63;
    int bm = blockIdx.x * 128 + (w & 1) * 64;
    int bn = blockIdx.y * 128 + (w >> 1) * 64;
    f4v acc[4][4];
    mfma_core<K, false>(Ah, Al, nullptr, Bh, Bl, bm, bn, lane, acc);
    int cn = lane & 15, cr = (lane >> 4) * 4;
    #pragma unroll
    for (int i = 0; i < 4; ++i) {
        int m0 = bm + i * 16 + cr;
        #pragma unroll
        for (int j = 0; j < 4; ++j) {
            int n = bn + j * 16 + cn;
            #pragma unroll
            for (int r = 0; r < 4; ++r)
                C[(size_t)(m0 + r) * ldC + n] = acc[i][j][r];
        }
    }
}

// mp-batched Q1 = o0 @ wq1 planes (K=256), blockIdx.z = mp.
__global__ __launch_bounds__(256) void k_q1(
        const u16* __restrict__ o0h, const u16* __restrict__ o0l, // [NMP][B][256]
        const u16* __restrict__ qth, const u16* __restrict__ qtl, // [NMP][256][256]
        float* __restrict__ Q1) {                                 // [NMP][B][256]
    int mp = blockIdx.z;
    const u16* Ah = o0h + (size_t)mp * B_TR * D1;
    const u16* Al = o0l + (size_t)mp * B_TR * D1;
    const u16* Bh = qth + (size_t)mp * 65536;
    const u16* Bl = qtl + (size_t)mp * 65536;
    float* C = Q1 + (size_t)mp * B_TR * D1;
    int w = threadIdx.x >> 6, lane = threadIdx.x & 63;
    int bm = blockIdx.x * 128 + (w & 1) * 64;
    int bn = blockIdx.y * 128 + (w >> 1) * 64;
    f4v acc[4][4];
    mfma_core<256, false>(Ah, Al, nullptr, Bh, Bl, bm, bn, lane, acc);
    int cn = lane & 15, cr = (lane >> 4) * 4;
    #pragma unroll
    for (int i = 0; i < 4; ++i) {
        int m0 = bm + i * 16 + cr;
        #pragma unroll
        for (int j = 0; j < 4; ++j) {
            int n = bn + j * 16 + cn;
            #pragma unroll
            for (int r = 0; r < 4; ++r)
                C[(size_t)(m0 + r) * D1 + n] = acc[i][j][r];
        }
    }
}

// ---------------------------------------------------------------------------
// mp-batched L0: K0 gather-MFMA (K=32) + node attention epilogue.
// Grid (NSLOT/128, 2, NMP), 256 thr. R2-verified body + mp offsets.
__global__ __launch_bounds__(256) void k_nattn0(
        const u16* __restrict__ ebh, const u16* __restrict__ ebl, // [NMP][E][32]
        const int* __restrict__ eid,                              // [NMP][NSLOT]
        const u16* __restrict__ k0h, const u16* __restrict__ k0l, // [NMP][256][32]
        const float* __restrict__ q0b,                            // [NMP][B][256]
        u16* __restrict__ o0hb, u16* __restrict__ o0lb,           // [NMP][B][256]
        float* __restrict__ xcat, u16* __restrict__ xhb, u16* __restrict__ xlb) {
    int mp = blockIdx.z;
    const u16* Ah = ebh + (size_t)mp * E_EDGES * E_DIMC;
    const u16* Al = ebl + (size_t)mp * E_EDGES * E_DIMC;
    const int* rows = eid + (size_t)mp * NSLOT;
    const u16* Bh = k0h + (size_t)mp * 8192;
    const u16* Bl = k0l + (size_t)mp * 8192;
    const float* q = q0b + (size_t)mp * B_TR * D1;
    u16* o0h = o0hb + (size_t)mp * B_TR * D1;
    u16* o0l = o0lb + (size_t)mp * B_TR * D1;
    float* xrow = xcat + (size_t)mp * B_TR * 2 * D1;
    u16* xh = xhb + (size_t)mp * B_TR * 2 * D1;
    u16* xl = xlb + (size_t)mp * B_TR * 2 * D1;

    int w = threadIdx.x >> 6, lane = threadIdx.x & 63;
    int rbase = blockIdx.x * 128 + (w & 1) * 64;
    int bn = blockIdx.y * 128 + (w >> 1) * 64;
    f4v acc[4][4];
    mfma_core<32, true>(Ah, Al, rows, Bh, Bl, rbase, bn, lane, acc);

    int cn = lane & 15, grp = lane >> 4;
    #pragma unroll
    for (int i = 0; i < 4; ++i) {
        int b = (rbase >> 4) + i;
        float qv[4];
        #pragma unroll
        for (int j = 0; j < 4; ++j)
            qv[j] = q[(size_t)b * D1 + bn + j * 16 + cn];
        float lg[4];
        #pragma unroll
        for (int r = 0; r < 4; ++r) {
            float p = 0.f;
            #pragma unroll
            for (int j = 0; j < 4; ++j) p += acc[i][j][r] * qv[j];
            lg[r] = grp16_sum(p) * 0.125f;
        }
        float mx = fmaxf(fmaxf(lg[0], lg[1]), fmaxf(lg[2], lg[3]));
        mx = fmaxf(mx, __shfl_xor(mx, 16, 64));
        mx = fmaxf(mx, __shfl_xor(mx, 32, 64));
        float e[4], s = 0.f;
        #pragma unroll
        for (int r = 0; r < 4; ++r) { e[r] = expf(lg[r] - mx); s += e[r]; }
        s += __shfl_xor(s, 16, 64);
        s += __shfl_xor(s, 32, 64);
        float inv = 1.f / s;
        #pragma unroll
        for (int j = 0; j < 4; ++j) {
            float ag = e[0] * acc[i][j][0] + e[1] * acc[i][j][1]
                     + e[2] * acc[i][j][2] + e[3] * acc[i][j][3];
            ag += __shfl_xor(ag, 16, 64);
            ag += __shfl_xor(ag, 32, 64);
            float v = eluf(qv[j] + ag * inv);
            if (grp == 0) {
                int col = bn + j * 16 + cn;
                xrow[(size_t)b * (2 * D1) + col] = v;
                u16 hh, ll; splitbf(v, hh, ll);
                xh[(size_t)b * (2 * D1) + col] = hh;
                xl[(size_t)b * (2 * D1) + col] = ll;
                o0h[(size_t)b * D1 + col] = hh;
                o0l[(size_t)b * D1 + col] = ll;
            }
        }
    }
}

// ---------------------------------------------------------------------------
// MEGA (8-wave, 64-slot, mp-batched, reg-prefetched): Qe gather-MFMA (K=32)
// -> edge-attn -> ned in LDS -> K1 MFMA (K=256) -> node-attn L1.
// R9: all Kn gather loads (kA/kB, 64/lane) + Q1 loads issued BEFORE phase-1
// MFMA (addresses known at entry) so global-load latency overlaps compute.
// Values/FP-order identical to R8. VGPR rise is free: LDS caps occupancy.
__global__ __launch_bounds__(512, 4) void k_mega(
        const u16* __restrict__ ebh, const u16* __restrict__ ebl, // [NMP][E][32]
        const int* __restrict__ eid,                              // [NMP][NSLOT]
        const u16* __restrict__ qeh, const u16* __restrict__ qel, // [NMP][256][32]
        const float* __restrict__ Knb,                            // [NMP][N][256]
        const int* __restrict__ adjAb, const int* __restrict__ adjBb,
        const u16* __restrict__ kth, const u16* __restrict__ ktl, // [NMP][256][256]
        const float* __restrict__ Q1b,                            // [NMP][B][256]
        float* __restrict__ xcat, u16* __restrict__ xhb, u16* __restrict__ xlb) {
    int mp = blockIdx.z;
    const u16* Ah = ebh + (size_t)mp * E_EDGES * E_DIMC;
    const u16* Al = ebl + (size_t)mp * E_EDGES * E_DIMC;
    const int* rows = eid + (size_t)mp * NSLOT;
    const u16* qBh = qeh + (size_t)mp * 8192;
    const u16* qBl = qel + (size_t)mp * 8192;
    const float* Kn = Knb + (size_t)mp * N_NODES * D1;
    const int* adjA = adjAb + (size_t)mp * NSLOT;
    const int* adjB = adjBb + (size_t)mp * NSLOT;
    const u16* kBh = kth + (size_t)mp * 65536;
    const u16* kBl = ktl + (size_t)mp * 65536;
    const float* q = Q1b + (size_t)mp * B_TR * D1;
    float* xrow = xcat + (size_t)mp * B_TR * 2 * D1;
    u16* xh = xhb + (size_t)mp * B_TR * 2 * D1;
    u16* xl = xlb + (size_t)mp * B_TR * 2 * D1;

    __shared__ u16 sh_[64][NPAD];
    __shared__ u16 sl_[64][NPAD];
    int w = threadIdx.x >> 6, lane = threadIdx.x & 63;
    int wr = w & 1, wc = w >> 1;
    int blk = blockIdx.x * 64;
    int rbase = blk + wr * 32;
    int bn = wc * 64;
    int fr = lane & 15, kq = (lane >> 4) * 8;
    int cn = lane & 15, cr = (lane >> 4) * 4;

    // adj row offsets for this wave's 8 (i,r) slots
    int raA[2][4], raB[2][4];
    #pragma unroll
    for (int i = 0; i < 2; ++i)
        #pragma unroll
        for (int r = 0; r < 4; ++r) {
            int slot = rbase + i * 16 + cr + r;
            raA[i][r] = adjA[slot] * D1;
            raB[i][r] = adjB[slot] * D1;
        }

    // ---- R9 prefetch: issue ALL Kn gathers + Q1 loads up front ----
    float kA[2][4][4], kB[2][4][4];
    #pragma unroll
    for (int i = 0; i < 2; ++i)
        #pragma unroll
        for (int r = 0; r < 4; ++r)
            #pragma unroll
            for (int j = 0; j < 4; ++j) {
                int col = bn + j * 16 + cn;
                kA[i][r][j] = Kn[(size_t)raA[i][r] + col];
                kB[i][r][j] = Kn[(size_t)raB[i][r] + col];
            }
    float qvp[2][4];
    #pragma unroll
    for (int i = 0; i < 2; ++i)
        #pragma unroll
        for (int j = 0; j < 4; ++j)
            qvp[i][j] = q[(size_t)((rbase >> 4) + i) * D1 + bn + j * 16 + cn];

    // ---- phase 1: Qe = emb[eid] @ Wqe (K=32, gather), M=32 N=64 ----
    f4v acc[2][4];
    #pragma unroll
    for (int i = 0; i < 2; ++i)
        #pragma unroll
        for (int j = 0; j < 4; ++j) acc[i][j] = f4v{0.f, 0.f, 0.f, 0.f};
    {
        s8v ah[2], al[2], bh[4], bl[4];
        #pragma unroll
        for (int i = 0; i < 2; ++i) {
            size_t ao = (size_t)rows[rbase + i * 16 + fr] * E_DIMC + kq;
            ah[i] = *(const s8v*)(Ah + ao);
            al[i] = *(const s8v*)(Al + ao);
        }
        #pragma unroll
        for (int j = 0; j < 4; ++j) {
            size_t bo = (size_t)(bn + j * 16 + fr) * E_DIMC + kq;
            bh[j] = *(const s8v*)(qBh + bo);
            bl[j] = *(const s8v*)(qBl + bo);
        }
        #pragma unroll
        for (int i = 0; i < 2; ++i)
            #pragma unroll
            for (int j = 0; j < 4; ++j) {
                acc[i][j] = __builtin_amdgcn_mfma_f32_16x16x32_bf16(al[i], bh[j], acc[i][j], 0, 0, 0);
                acc[i][j] = __builtin_amdgcn_mfma_f32_16x16x32_bf16(ah[i], bl[j], acc[i][j], 0, 0, 0);
                acc[i][j] = __builtin_amdgcn_mfma_f32_16x16x32_bf16(ah[i], bh[j], acc[i][j], 0, 0, 0);
            }
    }

    // ---- phase 2: edge attention epilogue (reg kA/kB) -> ned into LDS ----
    #pragma unroll
    for (int i = 0; i < 2; ++i) {
        #pragma unroll
        for (int r = 0; r < 4; ++r) {
            int lrow = wr * 32 + i * 16 + cr + r;
            float pA = 0.f, pB = 0.f;
            #pragma unroll
            for (int j = 0; j < 4; ++j) {
                pA += acc[i][j][r] * kA[i][r][j];
                pB += acc[i][j][r] * kB[i][r][j];
            }
            float lA = grp16_sum(pA) * 0.125f;
            float lB = grp16_sum(pB) * 0.125f;
            float m = fmaxf(lA, lB);
            float eA = expf(lA - m), eB = expf(lB - m);
            float inv = 1.f / (eA + eB);
            #pragma unroll
            for (int j = 0; j < 4; ++j) {
                int col = bn + j * 16 + cn;
                float v = eluf(acc[i][j][r] + (eA * kA[i][r][j] + eB * kB[i][r][j]) * inv);
                u16 hh, ll; splitbf(v, hh, ll);
                sh_[lrow][col] = hh;
                sl_[lrow][col] = ll;
            }
        }
    }
    __syncthreads();

    // ---- phase 3: K1 = ned @ wk1 (K=256, A from LDS), M=32 N=64 ----
    #pragma unroll
    for (int i = 0; i < 2; ++i)
        #pragma unroll
        for (int j = 0; j < 4; ++j) acc[i][j] = f4v{0.f, 0.f, 0.f, 0.f};
    #pragma unroll 2
    for (int k0 = 0; k0 < 256; k0 += 32) {
        s8v ah[2], al[2], bh[4], bl[4];
        #pragma unroll
        for (int i = 0; i < 2; ++i) {
            int lr = wr * 32 + i * 16 + fr;
            ah[i] = *(const s8v*)&sh_[lr][k0 + kq];
            al[i] = *(const s8v*)&sl_[lr][k0 + kq];
        }
        #pragma unroll
        for (int j = 0; j < 4; ++j) {
            size_t bo = (size_t)(bn + j * 16 + fr) * 256 + k0 + kq;
            bh[j] = *(const s8v*)(kBh + bo);
            bl[j] = *(const s8v*)(kBl + bo);
        }
        #pragma unroll
        for (int i = 0; i < 2; ++i)
            #pragma unroll
            for (int j = 0; j < 4; ++j) {
                acc[i][j] = __builtin_amdgcn_mfma_f32_16x16x32_bf16(al[i], bh[j], acc[i][j], 0, 0, 0);
                acc[i][j] = __builtin_amdgcn_mfma_f32_16x16x32_bf16(ah[i], bl[j], acc[i][j], 0, 0, 0);
                acc[i][j] = __builtin_amdgcn_mfma_f32_16x16x32_bf16(ah[i], bh[j], acc[i][j], 0, 0, 0);
            }
    }

    // ---- phase 4: node attention L1 epilogue (qv prefetched) ----
    int grp = lane >> 4;
    #pragma unroll
    for (int i = 0; i < 2; ++i) {
        int b = (rbase >> 4) + i;
        float lg[4];
        #pragma unroll
        for (int r = 0; r < 4; ++r) {
            float p = 0.f;
            #pragma unroll
            for (int j = 0; j < 4; ++j) p += acc[i][j][r] * qvp[i][j];
            lg[r] = grp16_sum(p) * 0.125f;
        }
        float mx = fmaxf(fmaxf(lg[0], lg[1]), fmaxf(lg[2], lg[3]));
        mx = fmaxf(mx, __shfl_xor(mx, 16, 64));
        mx = fmaxf(mx, __shfl_xor(mx, 32, 64));
        float e[4], s = 0.f;
        #pragma unroll
        for (int r = 0; r < 4; ++r) { e[r] = expf(lg[r] - mx); s += e[r]; }
        s += __shfl_xor(s, 16, 64);
        s += __shfl_xor(s, 32, 64);
        float inv = 1.f / s;
        #pragma unroll
        for (int j = 0; j < 4; ++j) {
            float ag = e[0] * acc[i][j][0] + e[1] * acc[i][j][1]
                     + e[2] * acc[i][j][2] + e[3] * acc[i][j][3];
            ag += __shfl_xor(ag, 16, 64);
            ag += __shfl_xor(ag, 32, 64);
            float v = eluf(qvp[i][j] + ag * inv);
            if (grp == 0) {
                int col = bn + j * 16 + cn;
                xrow[(size_t)b * (2 * D1) + D1 + col] = v;
                u16 hh, ll; splitbf(v, hh, ll);
                xh[(size_t)b * (2 * D1) + D1 + col] = hh;
                xl[(size_t)b * (2 * D1) + D1 + col] = ll;
            }
        }
    }
}

// ---------------------------------------------------------------------------
// slot tables (both mp in one launch)
__global__ void k_slot_setup2(const int* __restrict__ n2e,
                              const int* __restrict__ adj,
                              const int* __restrict__ tid,
                              int* __restrict__ eid,
                              int* __restrict__ adjA,
                              int* __restrict__ adjB) {
    int i = blockIdx.x * blockDim.x + threadIdx.x;
    if (i >= NMP * NSLOT) return;
    int mp = i / NSLOT, sl = i - mp * NSLOT;
    int b = sl >> 4, s = sl & 15;
    int e = n2e[(size_t)mp * N_NODES * S_NE + (size_t)tid[b] * S_NE + s];
    eid[i] = e;
    adjA[i] = adj[(size_t)mp * E_EDGES * 2 + (size_t)e * 2 + 0];
    adjB[i] = adj[(size_t)mp * E_EDGES * 2 + (size_t)e * 2 + 1];
}

// gate finish
template <typename T>
__device__ void gate_fin_body(const float* gmat, const void* vg, float* gate_pre) {
    int row = blockIdx.x;
    int t = threadIdx.x;   // 128
    float v = tanhf(gmat[(size_t)row * PREP + t]) * ldv<T>(vg, t);
    __shared__ float red[128];
    red[t] = v;
    __syncthreads();
    for (int s = 64; s > 0; s >>= 1) { if (t < s) red[t] += red[t + s]; __syncthreads(); }
    if (t == 0) gate_pre[row] = red[0];
}
__global__ void k_gate_fin(const float* gmat, const void* vg, float* gate_pre,
                           const int* flag) {
    if (*flag == 1) gate_fin_body<float>(gmat, vg, gate_pre);
    else            gate_fin_body<bf16 >(gmat, vg, gate_pre);
}

// fallback gate (direct from xcat)
template <typename T>
__device__ void gate_dir_body(const float* xcat, const void* Wg, const void* vg,
                              float* gate_pre) {
    int mb = blockIdx.x;
    int t = threadIdx.x;   // 128
    __shared__ float xr[2 * D1];
    for (int idx = t; idx < 2 * D1; idx += 128) xr[idx] = xcat[(size_t)mb * (2 * D1) + idx];
    __syncthreads();
    float acc = 0.f;
    for (int d = 0; d < 2 * D1; ++d) acc += xr[d] * ldv<T>(Wg, (size_t)d * PREP + t);
    float gp = tanhf(acc) * ldv<T>(vg, t);
    __shared__ float red[128];
    red[t] = gp;
    __syncthreads();
    for (int s = 64; s > 0; s >>= 1) { if (t < s) red[t] += red[t + s]; __syncthreads(); }
    if (t == 0) gate_pre[mb] = red[0];
}
__global__ void k_gate_direct(const float* xcat, const void* Wg, const void* vg,
                              float* gate_pre, const int* flag) {
    if (*flag == 1) gate_dir_body<float>(xcat, Wg, vg, gate_pre);
    else            gate_dir_body<bf16 >(xcat, Wg, vg, gate_pre);
}

// final
template <typename T>
__device__ void final_body(const float* xcat, const float* gate_pre,
                           const void* Wfc, const void* bfc, void* out) {
    int b = blockIdx.x;
    int t = threadIdx.x;  // 64
    float g0 = gate_pre[b], g1 = gate_pre[B_TR + b];
    float mx = fmaxf(g0, g1);
    float e0 = expf(g0 - mx), e1 = expf(g1 - mx);
    float inv = 1.f / (e0 + e1);
    float w0 = e0 * inv, w1 = e1 * inv;
    __shared__ float pooled[2 * D1];
    for (int d = t; d < 2 * D1; d += 64)
        pooled[d] = w0 * xcat[(size_t)b * (2 * D1) + d]
                  + w1 * xcat[(size_t)(B_TR + b) * (2 * D1) + d];
    __syncthreads();
    if (t < NCLS) {
        float acc = ldv<T>(bfc, t);
        for (int d = 0; d < 2 * D1; ++d) acc += pooled[d] * ldv<T>(Wfc, (size_t)d * NCLS + t);
        stv<T>(out, (size_t)b * NCLS + t, acc);
    }
    if (t == 8) stv<T>(out, (size_t)B_TR * NCLS + b, w0);
    if (t == 9) stv<T>(out, (size_t)B_TR * NCLS + B_TR + b, w1);
}
__global__ void k_final(const float* xcat, const float* gate_pre,
                        const void* Wfc, const void* bfc, void* out,
                        const int* flag) {
    if (*flag == 1) final_body<float>(xcat, gate_pre, Wfc, bfc, out);
    else            final_body<bf16 >(xcat, gate_pre, Wfc, bfc, out);
}

// ---------------------------------------------------------------------------
// Fallback kernels (R4-verified fused path)
template <typename T>
__global__ void k_prep_nodes(const void* __restrict__ feats,
                             const void* __restrict__ W,
                             float* __restrict__ out,
                             const int* __restrict__ flag) {
    if (!active<T>(flag)) return;
    int g = blockIdx.x * blockDim.x + threadIdx.x;
    if (g >= N_NODES * 32) return;
    int n = g >> 5, pg = g & 31;
    float4 acc; ZERO4(acc);
    #pragma unroll 8
    for (int d = 0; d < D_FEAT; ++d) {
        float f = ldv<T>(feats, (size_t)n * D_FEAT + d);
        float4 w4 = ld4<T>(W, (size_t)d * PREP + pg * 4);
        FMA4C(acc, f, w4);
    }
    *(float4*)(out + (size_t)n * PREP + pg * 4) = acc;
}

template <typename T>
__global__ __launch_bounds__(256) void k_fused(
        const void* __restrict__ feats,
        const void* __restrict__ edge_emb_mp,
        const void* __restrict__ W_prep0,
        const void* __restrict__ epw_mp,
        const void* __restrict__ ewq,
        const void* __restrict__ ewk,
        const void* __restrict__ nwq0,
        const void* __restrict__ nwk0,
        const void* __restrict__ nwq1,
        const void* __restrict__ nwk1,
        const int*  __restrict__ n2e_mp,
        const int*  __restrict__ adj_mp,
        const int*  __restrict__ tid,
        const float* __restrict__ all_feats0,
        float* __restrict__ xcat_mp,
        const int* __restrict__ flag) {
    if (!active<T>(flag)) return;
    int b = blockIdx.x;
    int t = threadIdx.x;
    int h = t >> 6;
    int lane = t & 63;
    int mg = lane & 3, og = lane >> 2;

    __shared__ int   s_eid[S_NE];
    __shared__ int   s_nrow[2 * S_NE];
    __shared__ __align__(16) float s_emb[S_NE * E_DIMC];
    __shared__ __align__(16) float s_f[D_FEAT];
    __shared__ __align__(16) float s_q0[PREP];
    __shared__ __align__(16) float s_eprep[S_NE * LDA0];
    __shared__ __align__(16) float s_xn_pool[2 * S_NE * LDA0];
    __shared__ __align__(16) float s_out0[D1];
    float* s_nedge = s_xn_pool;

    int tid_b = tid[b];
    if (t < S_NE)   s_eid[t] = n2e_mp[(size_t)tid_b * S_NE + t];
    if (t < D_FEAT) s_f[t] = ldv<T>(feats, (size_t)tid_b * D_FEAT + t);
    __syncthreads();

    if (t < 2 * S_NE) s_nrow[t] = adj_mp[(size_t)s_eid[t >> 1] * 2 + (t & 1)];
    {
        int j = t, s = j >> 5, d = j & 31;
        s_emb[j] = ldv<T>(edge_emb_mp, (size_t)s_eid[s] * E_DIMC + d);
        j = t + 256; s = j >> 5; d = j & 31;
        s_emb[j] = ldv<T>(edge_emb_mp, (size_t)s_eid[s] * E_DIMC + d);
    }
    if (t < PREP) {
        float a = 0.f;
        #pragma unroll
        for (int d = 0; d < D_FEAT; ++d) a += s_f[d] * ldv<T>(W_prep0, d * PREP + t);
        s_q0[t] = a;
    }
    __syncthreads();

    #pragma unroll
    for (int k = 0; k < 4; ++k) {
        int j = t + 256 * k;
        int r = j >> 5, dc = j & 31;
        float4 v = *(const float4*)(all_feats0 + (size_t)s_nrow[r] * PREP + dc * 4);
        *(float4*)&s_xn_pool[r * LDA0 + dc * 4] = v;
    }
    {
        int s = t >> 4, pg = t & 15;
        float4 a0, a1; ZERO4(a0); ZERO4(a1);
        #pragma unroll
        for (int d = 0; d < E_DIMC; ++d) {
            float e = s_emb[s * E_DIMC + d];
            float4 w0 = ld4<T>(epw_mp, (size_t)d * PREP + pg * 8);
            float4 w1 = ld4<T>(epw_mp, (size_t)d * PREP + pg * 8 + 4);
            FMA4C(a0, e, w0); FMA4C(a1, e, w1);
        }
        *(float4*)&s_eprep[s * LDA0 + pg * 8]     = a0;
        *(float4*)&s_eprep[s * LDA0 + pg * 8 + 4] = a1;
    }
    __syncthreads();

    float4 aq[4], ak[8];
    #pragma unroll
    for (int i = 0; i < 4; ++i) ZERO4(aq[i]);
    #pragma unroll
    for (int i = 0; i < 8; ++i) ZERO4(ak[i]);
    {
        size_t wb = (size_t)h * PREP * O_DIM + og * 4;
        for (int kk = 0; kk < PREP; kk += 4) {
            float4 bq[4], bk[4];
            #pragma unroll
            for (int j = 0; j < 4; ++j) {
                bq[j] = ld4<T>(ewq, wb + (size_t)(kk + j) * O_DIM);
                bk[j] = ld4<T>(ewk, wb + (size_t)(kk + j) * O_DIM);
            }
            #pragma unroll
            for (int i = 0; i < 4; ++i) {
                float4 a = *(const float4*)&s_eprep[(mg + 4 * i) * LDA0 + kk];
                FMA4C(aq[i], a.x, bq[0]); FMA4C(aq[i], a.y, bq[1]);
                FMA4C(aq[i], a.z, bq[2]); FMA4C(aq[i], a.w, bq[3]);
            }
            #pragma unroll
            for (int i = 0; i < 8; ++i) {
                int r = 2 * mg + (i & 1) + 8 * (i >> 1);
                float4 a = *(const float4*)&s_xn_pool[r * LDA0 + kk];
                FMA4C(ak[i], a.x, bk[0]); FMA4C(ak[i], a.y, bk[1]);
                FMA4C(ak[i], a.z, bk[2]); FMA4C(ak[i], a.w, bk[3]);
            }
        }
    }
    __syncthreads();

    #pragma unroll
    for (int j = 0; j < 4; ++j) {
        int s = mg + 4 * j;
        float4 q = aq[j], kA = ak[2 * j], kB = ak[2 * j + 1];
        float lA = og_sum(q.x * kA.x + q.y * kA.y + q.z * kA.z + q.w * kA.w) * 0.125f;
        float lB = og_sum(q.x * kB.x + q.y * kB.y + q.z * kB.z + q.w * kB.w) * 0.125f;
        float m = fmaxf(lA, lB);
        float eA = expf(lA - m), eB = expf(lB - m);
        float inv = 1.f / (eA + eB);
        float4 v;
        v.x = q.x + (eA * kA.x + eB * kB.x) * inv;
        v.y = q.y + (eA * kA.y + eB * kB.y) * inv;
        v.z = q.z + (eA * kA.z + eB * kB.z) * inv;
        v.w = q.w + (eA * kA.w + eB * kB.w) * inv;
        *(float4*)&s_nedge[s * LDA1 + h * O_DIM + og * 4] = elu4(v);
    }

    float4 zq; ZERO4(zq);
    float4 zk[4];
    #pragma unroll
    for (int i = 0; i < 4; ++i) ZERO4(zk[i]);
    {
        size_t wb = (size_t)h * PREP * O_DIM + og * 4;
        for (int kk = 0; kk < PREP; kk += 4) {
            float4 q4 = *(const float4*)&s_q0[kk];
            float4 bq[4], bk[4];
            #pragma unroll
            for (int j = 0; j < 4; ++j) {
                bq[j] = ld4<T>(nwq0, wb + (size_t)(kk + j) * O_DIM);
                bk[j] = ld4<T>(nwk0, wb + (size_t)(kk + j) * O_DIM);
            }
            FMA4C(zq, q4.x, bq[0]); FMA4C(zq, q4.y, bq[1]);
            FMA4C(zq, q4.z, bq[2]); FMA4C(zq, q4.w, bq[3]);
            #pragma unroll
            for (int i = 0; i < 4; ++i) {
                float4 a = *(const float4*)&s_eprep[(mg + 4 * i) * LDA0 + kk];
                FMA4C(zk[i], a.x, bk[0]); FMA4C(zk[i], a.y, bk[1]);
                FMA4C(zk[i], a.z, bk[2]); FMA4C(zk[i], a.w, bk[3]);
            }
        }
    }
    {
        float lg[4];
        #pragma unroll
        for (int j = 0; j < 4; ++j)
            lg[j] = og_sum(zq.x * zk[j].x + zq.y * zk[j].y +
                           zq.z * zk[j].z + zq.w * zk[j].w) * 0.125f;
        float mx = fmaxf(fmaxf(lg[0], lg[1]), fmaxf(lg[2], lg[3]));
        mx = mg_max(mx);
        float ea[4], ssum = 0.f;
        #pragma unroll
        for (int j = 0; j < 4; ++j) { ea[j] = expf(lg[j] - mx); ssum += ea[j]; }
        ssum = mg_sum(ssum);
        float inv = 1.f / ssum;
        float4 part; ZERO4(part);
        #pragma unroll
        for (int j = 0; j < 4; ++j) FMA4C(part, ea[j], zk[j]);
        part.x = mg_sum(part.x); part.y = mg_sum(part.y);
        part.z = mg_sum(part.z); part.w = mg_sum(part.w);
        float4 v;
        v.x = zq.x + part.x * inv; v.y = zq.y + part.y * inv;
        v.z = zq.z + part.z * inv; v.w = zq.w + part.w * inv;
        v = elu4(v);
        if (mg == 0) {
            *(float4*)&s_out0[h * O_DIM + og * 4] = v;
            *(float4*)(xcat_mp + (size_t)b * (2 * D1) + h * O_DIM + og * 4) = v;
        }
    }
    __syncthreads();

    ZERO4(zq);
    #pragma unroll
    for (int i = 0; i < 4; ++i) ZERO4(zk[i]);
    {
        size_t wb = (size_t)h * D1 * O_DIM + og * 4;
        for (int kk = 0; kk < D1; kk += 4) {
            float4 q4 = *(const float4*)&s_out0[kk];
            float4 bq[4], bk[4];
            #pragma unroll
            for (int j = 0; j < 4; ++j) {
                bq[j] = ld4<T>(nwq1, wb + (size_t)(kk + j) * O_DIM);
                bk[j] = ld4<T>(nwk1, wb + (size_t)(kk + j) * O_DIM);
            }
            FMA4C(zq, q4.x, bq[0]); FMA4C(zq, q4.y, bq[1]);
            FMA4C(zq, q4.z, bq[2]); FMA4C(zq, q4.w, bq[3]);
            #pragma unroll
            for (int i = 0; i < 4; ++i) {
                float4 a = *(const float4*)&s_nedge[(mg + 4 * i) * LDA1 + kk];
                FMA4C(zk[i], a.x, bk[0]); FMA4C(zk[i], a.y, bk[1]);
                FMA4C(zk[i], a.z, bk[2]); FMA4C(zk[i], a.w, bk[3]);
            }
        }
    }
    {
        float lg[4];
        #pragma unroll
        for (int j = 0; j < 4; ++j)
            lg[j] = og_sum(zq.x * zk[j].x + zq.y * zk[j].y +
                           zq.z * zk[j].z + zq.w * zk[j].w) * 0.125f;
        float mx = fmaxf(fmaxf(lg[0], lg[1]), fmaxf(lg[2], lg[3]));
        mx = mg_max(mx);
        float ea[4], ssum = 0.f;
        #pragma unroll
        for (int j = 0; j < 4; ++j) { ea[j] = expf(lg[j] - mx); ssum += ea[j]; }
        ssum = mg_sum(ssum);
        float inv = 1.f / ssum;
        float4 part; ZERO4(part);
        #pragma unroll
        for (int j = 0; j < 4; ++j) FMA4C(part, ea[j], zk[j]);
        part.x = mg_sum(part.x); part.y = mg_sum(part.y);
        part.z = mg_sum(part.z); part.w = mg_sum(part.w);
        float4 v;
        v.x = zq.x + part.x * inv; v.y = zq.y + part.y * inv;
        v.z = zq.z + part.z * inv; v.w = zq.w + part.w * inv;
        v = elu4(v);
        if (mg == 0)
            *(float4*)(xcat_mp + (size_t)b * (2 * D1) + D1 + h * O_DIM + og * 4) = v;
    }
}

// ---------------------------------------------------------------------------
extern "C" void kernel_launch(void* const* d_in, const int* in_sizes, int n_in,
                              void* d_out, int out_size, void* d_ws, size_t ws_size,
                              hipStream_t stream) {
    const void* feats       = d_in[0];
    const void* edge_emb    = d_in[1];
    const void* W_prep0     = d_in[2];
    const void* W_prep1     = d_in[3];
    const void* edge_prep_w = d_in[4];
    const void* e_wq0       = d_in[5];
    const void* e_wk0       = d_in[6];
    const void* n_wq0       = d_in[9];
    const void* n_wk0       = d_in[10];
    const void* n_wq1       = d_in[11];
    const void* n_wk1       = d_in[12];
    const void* Wg          = d_in[13];
    const void* vg          = d_in[14];
    const void* Wfc         = d_in[15];
    const void* bfc         = d_in[16];
    const int*  n2e         = (const int*)d_in[17];
    const int*  adj         = (const int*)d_in[18];
    const int*  tid         = (const int*)d_in[19];

    float* ws   = (float*)d_ws;
    int*   flag = (int*)ws;            // ws[0]
    float* base = ws + 4;
    size_t avail = (ws_size >= 16) ? (ws_size - 16) / 4 : 0;   // floats

    k_detect<<<1, 64, 0, stream>>>((const unsigned*)feats, flag);

    // ---- main-path fixed layout (float units; u16 buffers = n/2 floats) ----
    size_t off = 0;
    auto alloc = [&](size_t n) { size_t o = off; off += (n + 3) & ~(size_t)3; return o; };
    size_t o_xcat = alloc((size_t)NMP * B_TR * 2 * D1);       // 4.19M
    size_t o_gmat = alloc((size_t)NMP * B_TR * PREP);         // 1.05M
    size_t o_gpre = alloc(NMP * B_TR);
    size_t o_wkn  = alloc(NMP * 64 * D1);
    size_t o_wq0  = alloc(NMP * 64 * D1);
    size_t o_qeh  = alloc(NMP * 256 * 32 / 2);                // u16 planes
    size_t o_qel  = alloc(NMP * 256 * 32 / 2);
    size_t o_k0h  = alloc(NMP * 256 * 32 / 2);
    size_t o_k0l  = alloc(NMP * 256 * 32 / 2);
    size_t o_ebh  = alloc((size_t)NMP * E_EDGES * E_DIMC / 2); // 5.12M
    size_t o_ebl  = alloc((size_t)NMP * E_EDGES * E_DIMC / 2); // 5.12M
    size_t o_Kn   = alloc((size_t)NMP * N_NODES * D1);        // 10.24M
    size_t o_q0   = alloc((size_t)NMP * B_TR * D1);
    size_t o_Q1   = alloc((size_t)NMP * B_TR * D1);
    size_t o_eid  = alloc((size_t)NMP * NSLOT);
    size_t o_adjA = alloc((size_t)NMP * NSLOT);
    size_t o_adjB = alloc((size_t)NMP * NSLOT);
    size_t o_o0h  = alloc((size_t)NMP * B_TR * D1 / 2);
    size_t o_o0l  = alloc((size_t)NMP * B_TR * D1 / 2);
    size_t o_xh   = alloc((size_t)NMP * B_TR * D1);           // 512 u16/row
    size_t o_xl   = alloc((size_t)NMP * B_TR * D1);
    size_t o_wk1h = alloc((size_t)NMP * 32768);               // 256x256 u16
    size_t o_wk1l = alloc((size_t)NMP * 32768);
    size_t o_wq1h = alloc((size_t)NMP * 32768);
    size_t o_wq1l = alloc((size_t)NMP * 32768);
    size_t o_wgh  = alloc(32768);                             // 128x512 u16
    size_t o_wgl  = alloc(32768);
    size_t fixed = off;

    int CH = (fixed <= avail) ? B_TR : 0;

    if (CH > 0) {
        float* xcat = base + o_xcat;
        float* gmat = base + o_gmat;
        float* gpre = base + o_gpre;
        float* wkn  = base + o_wkn;
        float* wq0  = base + o_wq0;
        u16*   qeh  = (u16*)(base + o_qeh);
        u16*   qel  = (u16*)(base + o_qel);
        u16*   k0h  = (u16*)(base + o_k0h);
        u16*   k0l  = (u16*)(base + o_k0l);
        u16*   ebh  = (u16*)(base + o_ebh);
        u16*   ebl  = (u16*)(base + o_ebl);
        float* Kn   = base + o_Kn;
        float* q0   = base + o_q0;
        float* Q1   = base + o_Q1;
        int*   eid  = (int*)(base + o_eid);
        int*   adjA = (int*)(base + o_adjA);
        int*   adjB = (int*)(base + o_adjB);
        u16*   o0h  = (u16*)(base + o_o0h);
        u16*   o0l  = (u16*)(base + o_o0l);
        u16*   xh   = (u16*)(base + o_xh);
        u16*   xl   = (u16*)(base + o_xl);
        u16*   wk1h = (u16*)(base + o_wk1h);
        u16*   wk1l = (u16*)(base + o_wk1l);
        u16*   wq1h = (u16*)(base + o_wq1h);
        u16*   wq1l = (u16*)(base + o_wq1l);
        u16*   wgh  = (u16*)(base + o_wgh);
        u16*   wgl  = (u16*)(base + o_wgl);

        // ---- preprocessing (mp-batched already) ----
        k_precomb2<<<384, 256, 0, stream>>>(edge_prep_w, e_wq0, n_wk0, W_prep1,
                                            e_wk0, W_prep0, n_wq0,
                                            wkn, wq0, qeh, qel, k0h, k0l, flag);
        k_embsplit<<<(NMP * E_EDGES * E_DIMC + 255) / 256, 256, 0, stream>>>(
            edge_emb, ebh, ebl, flag);
        k_wt1<<<1024, 256, 0, stream>>>(n_wk1, n_wq1, wk1h, wk1l, wq1h, wq1l, flag);
        k_wgt<<<256, 256, 0, stream>>>(Wg, wgh, wgl, flag);
        k_slot_setup2<<<(NMP * NSLOT + 255) / 256, 256, 0, stream>>>(
            n2e, adj, tid, eid, adjA, adjB);

        // ---- main chain, one launch per stage (blockIdx.z = mp) ----
        // Kn[mp] = feats @ Wkn[mp]   [N,256], K=64
        k_gemm_rf<<<dim3((N_NODES + 63) / 64, 4, NMP), 256, 0, stream>>>(
            feats, 0, nullptr, D_FEAT,
            wkn, (size_t)64 * D1, 64, D1,
            Kn, (size_t)N_NODES * D1, D1, N_NODES, D_FEAT, flag);
        // q0[mp] = feats[tid] @ Wq0[mp]   [B,256], K=64
        k_gemm_rf<<<dim3(B_TR / 64, 4, NMP), 256, 0, stream>>>(
            feats, 0, tid, D_FEAT,
            wq0, (size_t)64 * D1, 64, D1,
            q0, (size_t)B_TR * D1, D1, B_TR, D_FEAT, flag);
        // L0: K0 gather-MFMA + node attn -> o0 planes + xcat[:,0:256]
        k_nattn0<<<dim3(NSLOT / 128, 2, NMP), 256, 0, stream>>>(
            ebh, ebl, eid, k0h, k0l, q0, o0h, o0l, xcat, xh, xl);
        // Q1[mp] = o0[mp] @ nwq1[mp]  (MFMA, K=256)
        k_q1<<<dim3(B_TR / 128, 2, NMP), 256, 0, stream>>>(
            o0h, o0l, wq1h, wq1l, Q1);
        // MEGA: Qe + edge attn + K1 + node attn L1 (ned in LDS, reg-prefetch)
        k_mega<<<dim3(NSLOT / 64, 1, NMP), 512, 0, stream>>>(
            ebh, ebl, eid, qeh, qel, Kn, adjA, adjB,
            wk1h, wk1l, Q1, xcat, xh, xl);

        // gate: gmat = xcat @ Wg  [8192,128], K=512 (MFMA from x planes)
        k_mfma<512><<<dim3(NMP * B_TR / 128, 1), 256, 0, stream>>>(
            xh, xl, wgh, wgl, gmat, PREP);
        k_gate_fin<<<NMP * B_TR, 128, 0, stream>>>(gmat, vg, gpre, flag);
        k_final<<<B_TR, 64, 0, stream>>>(xcat, gpre, Wfc, bfc, d_out, flag);
    } else {
        // ------------- fused fallback (R4) -------------
        size_t f_off = 0;
        auto falloc = [&](size_t n) { size_t o = f_off; f_off += (n + 3) & ~(size_t)3; return o; };
        float* af0  = base + falloc((size_t)N_NODES * PREP);
        float* xcat = base + falloc((size_t)NMP * B_TR * 2 * D1);
        float* gpre = base + falloc(NMP * B_TR);

        k_prep_nodes<float><<<(N_NODES * 32 + 255) / 256, 256, 0, stream>>>(
            feats, W_prep1, af0, flag);
        k_prep_nodes<bf16><<<(N_NODES * 32 + 255) / 256, 256, 0, stream>>>(
            feats, W_prep1, af0, flag);

        for (int mp = 0; mp < NMP; ++mp) {
            #define FUSED_ARGS(esz)                                                   \
                feats,                                                                \
                (const char*)edge_emb + (esz) * (size_t)mp * E_EDGES * E_DIMC,        \
                W_prep0,                                                              \
                (const char*)edge_prep_w + (esz) * (size_t)mp * E_DIMC * PREP,        \
                (const char*)e_wq0 + (esz) * (size_t)mp * H_HEADS * PREP * O_DIM,     \
                (const char*)e_wk0 + (esz) * (size_t)mp * H_HEADS * PREP * O_DIM,     \
                (const char*)n_wq0 + (esz) * (size_t)mp * H_HEADS * PREP * O_DIM,     \
                (const char*)n_wk0 + (esz) * (size_t)mp * H_HEADS * PREP * O_DIM,     \
                (const char*)n_wq1 + (esz) * (size_t)mp * H_HEADS * D1 * O_DIM,       \
                (const char*)n_wk1 + (esz) * (size_t)mp * H_HEADS * D1 * O_DIM,       \
                n2e + (size_t)mp * N_NODES * S_NE,                                    \
                adj + (size_t)mp * E_EDGES * 2,                                       \
                tid, af0, xcat + (size_t)mp * B_TR * 2 * D1, flag
            k_fused<float><<<B_TR, 256, 0, stream>>>(FUSED_ARGS(4));
            k_fused<bf16><<<B_TR, 256, 0, stream>>>(FUSED_ARGS(2));
            #undef FUSED_ARGS
        }
        k_gate_direct<<<NMP * B_TR, 128, 0, stream>>>(xcat, Wg, vg, gpre, flag);
        k_final<<<B_TR, 64, 0, stream>>>(xcat, gpre, Wfc, bfc, d_out, flag);
    }
}

// Round 10
// 485.239 us; speedup vs baseline: 1.0451x; 1.0451x over previous
//
#include <hip/hip_runtime.h>
#include <hip/hip_bf16.h>
#include <math.h>

// Problem dims
#define N_NODES 20000
#define S_NE    16
#define E_EDGES 160000
#define NMP     2
#define H_HEADS 4
#define O_DIM   64
#define D_FEAT  64
#define E_DIMC  32
#define PREP    128
#define NCLS    8
#define B_TR    4096
#define D1      256           // H*O
#define NSLOT   (B_TR * S_NE) // 65536

// LDS row pads for fused fallback
#define LDA0    132
#define LDA1    260
// LDS ned plane pad (u16 units): 256+8 -> row stride 528B, bank-balanced b128
#define NPAD    264

typedef __hip_bfloat16 bf16;
typedef unsigned short u16;
typedef __attribute__((ext_vector_type(8))) short s8v;   // 8 bf16 (4 VGPRs)
typedef __attribute__((ext_vector_type(4))) float f4v;   // MFMA acc

template <typename T>
__device__ __forceinline__ float ldv(const void* p, size_t i) {
    if constexpr (sizeof(T) == 4) return ((const float*)p)[i];
    else return __bfloat162float(((const bf16*)p)[i]);
}
template <typename T>
__device__ __forceinline__ float4 ld4(const void* p, size_t i) {
    if constexpr (sizeof(T) == 4) {
        return *(const float4*)((const float*)p + i);
    } else {
        float4 r;
        r.x = ldv<T>(p, i); r.y = ldv<T>(p, i + 1);
        r.z = ldv<T>(p, i + 2); r.w = ldv<T>(p, i + 3);
        return r;
    }
}
template <typename T>
__device__ __forceinline__ void stv(void* p, size_t i, float v) {
    if constexpr (sizeof(T) == 4) ((float*)p)[i] = v;
    else ((bf16*)p)[i] = __float2bfloat16(v);
}
template <typename T>
__device__ __forceinline__ bool active(const int* flag) {
    return *flag == (sizeof(T) == 4 ? 1 : 0);
}

__device__ __forceinline__ u16 f2bf(float x) {
    bf16 h = __float2bfloat16(x);
    return *reinterpret_cast<u16*>(&h);
}
__device__ __forceinline__ float bf2f(u16 u) {
    bf16 h; *reinterpret_cast<u16*>(&h) = u;
    return __bfloat162float(h);
}
// split-bf16: x ~= hi + lo, product error ~2^-17 relative
__device__ __forceinline__ void splitbf(float x, u16& h, u16& l) {
    h = f2bf(x);
    l = f2bf(x - bf2f(h));
}

__device__ __forceinline__ float wave_sum(float v) {
    #pragma unroll
    for (int off = 32; off > 0; off >>= 1) v += __shfl_xor(v, off, 64);
    return v;
}
__device__ __forceinline__ float og_sum(float v) {
    v += __shfl_xor(v, 4, 64);  v += __shfl_xor(v, 8, 64);
    v += __shfl_xor(v, 16, 64); v += __shfl_xor(v, 32, 64);
    return v;
}
// sum within 16-lane group (lanes sharing lane>>4)
__device__ __forceinline__ float grp16_sum(float v) {
    v += __shfl_xor(v, 1, 64); v += __shfl_xor(v, 2, 64);
    v += __shfl_xor(v, 4, 64); v += __shfl_xor(v, 8, 64);
    return v;
}
__device__ __forceinline__ float mg_sum(float v) {
    v += __shfl_xor(v, 1, 64); v += __shfl_xor(v, 2, 64); return v;
}
__device__ __forceinline__ float mg_max(float v) {
    v = fmaxf(v, __shfl_xor(v, 1, 64)); v = fmaxf(v, __shfl_xor(v, 2, 64)); return v;
}
__device__ __forceinline__ float eluf(float x) { return x > 0.f ? x : expf(x) - 1.f; }
__device__ __forceinline__ float4 elu4(float4 v) {
    v.x = eluf(v.x); v.y = eluf(v.y); v.z = eluf(v.z); v.w = eluf(v.w); return v;
}

#define FMA4C(acc, s, b) do { (acc).x += (s)*(b).x; (acc).y += (s)*(b).y; \
                              (acc).z += (s)*(b).z; (acc).w += (s)*(b).w; } while (0)
#define ZERO4(v) do { (v).x = 0.f; (v).y = 0.f; (v).z = 0.f; (v).w = 0.f; } while (0)

// ---------------------------------------------------------------------------
// Dtype detector (R3-verified): flag=1 => fp32 buffers. flag at ws[0].
__global__ void k_detect(const unsigned* __restrict__ w, int* __restrict__ flag) {
    int t = threadIdx.x;
    int bad = 0;
    for (int i = t; i < 512; i += 64) {
        float v = __uint_as_float((w[i] & 0xffffu) << 16);
        if (!(fabsf(v) < 64.f)) bad++;
    }
    #pragma unroll
    for (int off = 32; off > 0; off >>= 1) bad += __shfl_xor(bad, off, 64);
    if (t == 0) *flag = (bad > 32) ? 1 : 0;
}

// ---------------------------------------------------------------------------
// Parallel precombined weights (one thread per output element, 98304 total):
//  c0: Wqe planes [mp][n=256][k=32] = (epw @ ewq)^T hi/lo     (MFMA B operand)
//  c1: Wk0 planes [mp][n=256][k=32] = (epw @ nwk0)^T hi/lo
//  c2: Wkn fp32 [mp][64][256] = Wp1 @ ewk                     (fp32 GEMM B)
//  c3: Wq0 fp32 [mp][64][256] = Wp0 @ nwq0
template <typename T>
__device__ void precomb2_body(const void* epw, const void* ewq, const void* nwk0,
                              const void* Wp1, const void* ewk,
                              const void* Wp0, const void* nwq0,
                              float* wkn, float* wq0,
                              u16* qeh, u16* qel, u16* k0h, u16* k0l) {
    int idx = blockIdx.x * 256 + threadIdx.x;
    if (idx >= 98304) return;
    int combo, rem;
    if (idx < 16384)      { combo = 0; rem = idx; }
    else if (idx < 32768) { combo = 1; rem = idx - 16384; }
    else if (idx < 65536) { combo = 2; rem = idx - 32768; }
    else                  { combo = 3; rem = idx - 65536; }
    int mp, r, n;
    if (combo < 2) { mp = rem >> 13; r = (rem >> 8) & 31; n = rem & 255; }
    else           { mp = rem >> 14; r = (rem >> 8) & 63; n = rem & 255; }
    int h = n >> 6, o = n & 63;
    const void* Aw; const void* Bw; size_t aoff;
    size_t boff = (size_t)mp * H_HEADS * PREP * O_DIM + (size_t)h * PREP * O_DIM + o;
    switch (combo) {
        case 0: Aw = epw; Bw = ewq;  aoff = (size_t)mp * E_DIMC * PREP + (size_t)r * PREP; break;
        case 1: Aw = epw; Bw = nwk0; aoff = (size_t)mp * E_DIMC * PREP + (size_t)r * PREP; break;
        case 2: Aw = Wp1; Bw = ewk;  aoff = (size_t)r * PREP; break;
        default:Aw = Wp0; Bw = nwq0; aoff = (size_t)r * PREP; break;
    }
    float acc = 0.f;
    #pragma unroll 4
    for (int p = 0; p < PREP; ++p)
        acc += ldv<T>(Aw, aoff + p) * ldv<T>(Bw, boff + (size_t)p * O_DIM);
    if (combo < 2) {
        u16 hh, ll; splitbf(acc, hh, ll);
        size_t dst = (size_t)mp * (256 * 32) + (size_t)n * 32 + r;
        if (combo == 0) { qeh[dst] = hh; qel[dst] = ll; }
        else            { k0h[dst] = hh; k0l[dst] = ll; }
    } else if (combo == 2) {
        wkn[(size_t)mp * 64 * D1 + (size_t)r * D1 + n] = acc;
    } else {
        wq0[(size_t)mp * 64 * D1 + (size_t)r * D1 + n] = acc;
    }
}
__global__ void k_precomb2(const void* epw, const void* ewq, const void* nwk0,
                           const void* Wp1, const void* ewk,
                           const void* Wp0, const void* nwq0,
                           float* wkn, float* wq0,
                           u16* qeh, u16* qel, u16* k0h, u16* k0l,
                           const int* flag) {
    if (*flag == 1) precomb2_body<float>(epw, ewq, nwk0, Wp1, ewk, Wp0, nwq0, wkn, wq0, qeh, qel, k0h, k0l);
    else            precomb2_body<bf16 >(epw, ewq, nwk0, Wp1, ewk, Wp0, nwq0, wkn, wq0, qeh, qel, k0h, k0l);
}

// edge_emb -> hi/lo bf16 planes [NMP][E][32] (coalesced)
template <typename T>
__device__ void embsplit_body(const void* emb, u16* eh, u16* el) {
    size_t idx = (size_t)blockIdx.x * 256 + threadIdx.x;
    if (idx >= (size_t)NMP * E_EDGES * E_DIMC) return;
    float v = ldv<T>(emb, idx);
    u16 hh, ll; splitbf(v, hh, ll);
    eh[idx] = hh; el[idx] = ll;
}
__global__ void k_embsplit(const void* emb, u16* eh, u16* el, const int* flag) {
    if (*flag == 1) embsplit_body<float>(emb, eh, el);
    else            embsplit_body<bf16 >(emb, eh, el);
}

// Transposed hi/lo planes of nwk1/nwq1: Bt[mp][n=256][k=256]
template <typename T>
__device__ void wt1_body(const void* wk1, const void* wq1,
                         u16* kth, u16* ktl, u16* qth, u16* qtl) {
    int idx = blockIdx.x * 256 + threadIdx.x;   // 0..262143
    int k = idx & 255, n = (idx >> 8) & 255;
    int wsel = (idx >> 16) & 1, mp = idx >> 17;
    size_t src = (size_t)mp * (H_HEADS * D1 * O_DIM) + (size_t)(n >> 6) * (D1 * O_DIM)
               + (size_t)k * O_DIM + (n & 63);
    float v = ldv<T>(wsel ? wq1 : wk1, src);
    u16 h, l; splitbf(v, h, l);
    size_t dst = (size_t)mp * 65536 + (size_t)n * 256 + k;
    if (wsel) { qth[dst] = h; qtl[dst] = l; }
    else      { kth[dst] = h; ktl[dst] = l; }
}
__global__ void k_wt1(const void* wk1, const void* wq1,
                      u16* kth, u16* ktl, u16* qth, u16* qtl, const int* flag) {
    if (*flag == 1) wt1_body<float>(wk1, wq1, kth, ktl, qth, qtl);
    else            wt1_body<bf16 >(wk1, wq1, kth, ktl, qth, qtl);
}

// Transposed hi/lo planes of Wg[512][128] -> Wgt[n=128][k=512]
template <typename T>
__device__ void wgt_body(const void* Wg, u16* gh, u16* gl) {
    int idx = blockIdx.x * 256 + threadIdx.x;   // 0..65535
    int n = idx >> 9, k = idx & 511;
    float v = ldv<T>(Wg, (size_t)k * PREP + n);
    u16 h, l; splitbf(v, h, l);
    gh[(size_t)n * 512 + k] = h;
    gl[(size_t)n * 512 + k] = l;
}
__global__ void k_wgt(const void* Wg, u16* gh, u16* gl, const int* flag) {
    if (*flag == 1) wgt_body<float>(Wg, gh, gl);
    else            wgt_body<bf16 >(Wg, gh, gl);
}

// ---------------------------------------------------------------------------
// fp32 register-tiled GEMM (R6-verified), mp-batched via blockIdx.z strides.
template <typename TA, typename TB>
__device__ void gemm_body(const void* A, size_t aOff, const int* Aidx, int strideA,
                          const float* B, int sH, int sD,
                          float* C, int ldC, int M, int K) {
    int bm = blockIdx.x * 64;
    int h  = blockIdx.y;
    int t  = threadIdx.x;
    int tx = t & 15, ty = t >> 4;

    __shared__ float As[32][68];
    __shared__ float Bs[32][68];

    float acc[4][4] = {{0.f}};
    int arow = t >> 3, kq = (t & 7) * 4;
    int brow = t >> 4, nq = (t & 15) * 4;

    for (int k0 = 0; k0 < K; k0 += 32) {
        #pragma unroll
        for (int c = 0; c < 2; ++c) {
            int rm = arow + 32 * c;
            int gr = bm + rm;
            gr = (gr < M) ? gr : 0;
            size_t row = Aidx ? (size_t)Aidx[gr] : (size_t)gr;
            float4 a = ld4<TA>(A, aOff + row * strideA + k0 + kq);
            As[kq + 0][rm] = a.x; As[kq + 1][rm] = a.y;
            As[kq + 2][rm] = a.z; As[kq + 3][rm] = a.w;
        }
        #pragma unroll
        for (int c = 0; c < 2; ++c) {
            int rk = brow + 16 * c;
            float4 b = ld4<float>(B, (size_t)h * sH + (size_t)(k0 + rk) * sD + nq);
            *(float4*)&Bs[rk][nq] = b;
        }
        __syncthreads();
        #pragma unroll
        for (int kk = 0; kk < 32; ++kk) {
            float4 av = *(const float4*)&As[kk][ty * 4];
            float4 bv = *(const float4*)&Bs[kk][tx * 4];
            float am[4] = {av.x, av.y, av.z, av.w};
            #pragma unroll
            for (int i = 0; i < 4; ++i) {
                acc[i][0] += am[i] * bv.x; acc[i][1] += am[i] * bv.y;
                acc[i][2] += am[i] * bv.z; acc[i][3] += am[i] * bv.w;
            }
        }
        __syncthreads();
    }
    #pragma unroll
    for (int i = 0; i < 4; ++i) {
        int m = bm + ty * 4 + i;
        if (m < M) {
            float4 st; st.x = acc[i][0]; st.y = acc[i][1];
            st.z = acc[i][2]; st.w = acc[i][3];
            *(float4*)&C[(size_t)m * ldC + h * 64 + tx * 4] = st;
        }
    }
}
__global__ __launch_bounds__(256) void k_gemm_rf(
        const void* A, size_t aOff, const int* Aidx, int strideA,
        const float* B, size_t bStride, int sH, int sD,
        float* C, size_t cStride, int ldC, int M, int K,
        const int* flag) {
    const float* Bz = B + (size_t)blockIdx.z * bStride;
    float* Cz = C + (size_t)blockIdx.z * cStride;
    if (*flag == 1) gemm_body<float, float>(A, aOff, Aidx, strideA, Bz, sH, sD, Cz, ldC, M, K);
    else            gemm_body<bf16,  float>(A, aOff, Aidx, strideA, Bz, sH, sD, Cz, ldC, M, K);
}

// ---------------------------------------------------------------------------
// Shared split-bf16 MFMA mainloop (R7-verified structure).
template <int K, bool G>
__device__ __forceinline__ void mfma_core(
        const u16* __restrict__ Ah, const u16* __restrict__ Al,
        const int* __restrict__ rows,
        const u16* __restrict__ Bh, const u16* __restrict__ Bl,
        int rbase, int bn, int lane, f4v acc[4][4]) {
    int fr = lane & 15;
    int kq = (lane >> 4) * 8;
    #pragma unroll
    for (int i = 0; i < 4; ++i)
        #pragma unroll
        for (int j = 0; j < 4; ++j) acc[i][j] = f4v{0.f, 0.f, 0.f, 0.f};
    #pragma unroll 2
    for (int k0 = 0; k0 < K; k0 += 32) {
        s8v ah[4], al[4], bh[4], bl[4];
        #pragma unroll
        for (int i = 0; i < 4; ++i) {
            size_t arow;
            if constexpr (G) arow = (size_t)rows[rbase + i * 16 + fr];
            else             arow = (size_t)(rbase + i * 16 + fr);
            size_t ao = arow * K + k0 + kq;
            ah[i] = *(const s8v*)(Ah + ao);
            al[i] = *(const s8v*)(Al + ao);
            size_t bo = (size_t)(bn + i * 16 + fr) * K + k0 + kq;
            bh[i] = *(const s8v*)(Bh + bo);
            bl[i] = *(const s8v*)(Bl + bo);
        }
        #pragma unroll
        for (int i = 0; i < 4; ++i)
            #pragma unroll
            for (int j = 0; j < 4; ++j) {
                acc[i][j] = __builtin_amdgcn_mfma_f32_16x16x32_bf16(al[i], bh[j], acc[i][j], 0, 0, 0);
                acc[i][j] = __builtin_amdgcn_mfma_f32_16x16x32_bf16(ah[i], bl[j], acc[i][j], 0, 0, 0);
                acc[i][j] = __builtin_amdgcn_mfma_f32_16x16x32_bf16(ah[i], bh[j], acc[i][j], 0, 0, 0);
            }
    }
}

// Plain-store MFMA GEMM (gate): C = A @ B^T-planes.
template <int K>
__global__ __launch_bounds__(256) void k_mfma(
        const u16* __restrict__ Ah, const u16* __restrict__ Al,
        const u16* __restrict__ Bh, const u16* __restrict__ Bl,
        float* __restrict__ C, int ldC) {
    int w = threadIdx.x >> 6, lane = threadIdx.x & 63;
    int bm = blockIdx.x * 128 + (w & 1) * 64;
    int bn = blockIdx.y * 128 + (w >> 1) * 64;
    f4v acc[4][4];
    mfma_core<K, false>(Ah, Al, nullptr, Bh, Bl, bm, bn, lane, acc);
    int cn = lane & 15, cr = (lane >> 4) * 4;
    #pragma unroll
    for (int i = 0; i < 4; ++i) {
        int m0 = bm + i * 16 + cr;
        #pragma unroll
        for (int j = 0; j < 4; ++j) {
            int n = bn + j * 16 + cn;
            #pragma unroll
            for (int r = 0; r < 4; ++r)
                C[(size_t)(m0 + r) * ldC + n] = acc[i][j][r];
        }
    }
}

// mp-batched Q1 = o0 @ wq1 planes (K=256), blockIdx.z = mp.
__global__ __launch_bounds__(256) void k_q1(
        const u16* __restrict__ o0h, const u16* __restrict__ o0l, // [NMP][B][256]
        const u16* __restrict__ qth, const u16* __restrict__ qtl, // [NMP][256][256]
        float* __restrict__ Q1) {                                 // [NMP][B][256]
    int mp = blockIdx.z;
    const u16* Ah = o0h + (size_t)mp * B_TR * D1;
    const u16* Al = o0l + (size_t)mp * B_TR * D1;
    const u16* Bh = qth + (size_t)mp * 65536;
    const u16* Bl = qtl + (size_t)mp * 65536;
    float* C = Q1 + (size_t)mp * B_TR * D1;
    int w = threadIdx.x >> 6, lane = threadIdx.x & 63;
    int bm = blockIdx.x * 128 + (w & 1) * 64;
    int bn = blockIdx.y * 128 + (w >> 1) * 64;
    f4v acc[4][4];
    mfma_core<256, false>(Ah, Al, nullptr, Bh, Bl, bm, bn, lane, acc);
    int cn = lane & 15, cr = (lane >> 4) * 4;
    #pragma unroll
    for (int i = 0; i < 4; ++i) {
        int m0 = bm + i * 16 + cr;
        #pragma unroll
        for (int j = 0; j < 4; ++j) {
            int n = bn + j * 16 + cn;
            #pragma unroll
            for (int r = 0; r < 4; ++r)
                C[(size_t)(m0 + r) * D1 + n] = acc[i][j][r];
        }
    }
}

// ---------------------------------------------------------------------------
// mp-batched L0: K0 gather-MFMA (K=32) + node attention epilogue.
// Grid (NSLOT/128, 2, NMP), 256 thr. R2-verified body + mp offsets.
__global__ __launch_bounds__(256) void k_nattn0(
        const u16* __restrict__ ebh, const u16* __restrict__ ebl, // [NMP][E][32]
        const int* __restrict__ eid,                              // [NMP][NSLOT]
        const u16* __restrict__ k0h, const u16* __restrict__ k0l, // [NMP][256][32]
        const float* __restrict__ q0b,                            // [NMP][B][256]
        u16* __restrict__ o0hb, u16* __restrict__ o0lb,           // [NMP][B][256]
        float* __restrict__ xcat, u16* __restrict__ xhb, u16* __restrict__ xlb) {
    int mp = blockIdx.z;
    const u16* Ah = ebh + (size_t)mp * E_EDGES * E_DIMC;
    const u16* Al = ebl + (size_t)mp * E_EDGES * E_DIMC;
    const int* rows = eid + (size_t)mp * NSLOT;
    const u16* Bh = k0h + (size_t)mp * 8192;
    const u16* Bl = k0l + (size_t)mp * 8192;
    const float* q = q0b + (size_t)mp * B_TR * D1;
    u16* o0h = o0hb + (size_t)mp * B_TR * D1;
    u16* o0l = o0lb + (size_t)mp * B_TR * D1;
    float* xrow = xcat + (size_t)mp * B_TR * 2 * D1;
    u16* xh = xhb + (size_t)mp * B_TR * 2 * D1;
    u16* xl = xlb + (size_t)mp * B_TR * 2 * D1;

    int w = threadIdx.x >> 6, lane = threadIdx.x & 63;
    int rbase = blockIdx.x * 128 + (w & 1) * 64;
    int bn = blockIdx.y * 128 + (w >> 1) * 64;
    f4v acc[4][4];
    mfma_core<32, true>(Ah, Al, rows, Bh, Bl, rbase, bn, lane, acc);

    int cn = lane & 15, grp = lane >> 4;
    #pragma unroll
    for (int i = 0; i < 4; ++i) {
        int b = (rbase >> 4) + i;
        float qv[4];
        #pragma unroll
        for (int j = 0; j < 4; ++j)
            qv[j] = q[(size_t)b * D1 + bn + j * 16 + cn];
        float lg[4];
        #pragma unroll
        for (int r = 0; r < 4; ++r) {
            float p = 0.f;
            #pragma unroll
            for (int j = 0; j < 4; ++j) p += acc[i][j][r] * qv[j];
            lg[r] = grp16_sum(p) * 0.125f;
        }
        float mx = fmaxf(fmaxf(lg[0], lg[1]), fmaxf(lg[2], lg[3]));
        mx = fmaxf(mx, __shfl_xor(mx, 16, 64));
        mx = fmaxf(mx, __shfl_xor(mx, 32, 64));
        float e[4], s = 0.f;
        #pragma unroll
        for (int r = 0; r < 4; ++r) { e[r] = expf(lg[r] - mx); s += e[r]; }
        s += __shfl_xor(s, 16, 64);
        s += __shfl_xor(s, 32, 64);
        float inv = 1.f / s;
        #pragma unroll
        for (int j = 0; j < 4; ++j) {
            float ag = e[0] * acc[i][j][0] + e[1] * acc[i][j][1]
                     + e[2] * acc[i][j][2] + e[3] * acc[i][j][3];
            ag += __shfl_xor(ag, 16, 64);
            ag += __shfl_xor(ag, 32, 64);
            float v = eluf(qv[j] + ag * inv);
            if (grp == 0) {
                int col = bn + j * 16 + cn;
                xrow[(size_t)b * (2 * D1) + col] = v;
                u16 hh, ll; splitbf(v, hh, ll);
                xh[(size_t)b * (2 * D1) + col] = hh;
                xl[(size_t)b * (2 * D1) + col] = ll;
                o0h[(size_t)b * D1 + col] = hh;
                o0l[(size_t)b * D1 + col] = ll;
            }
        }
    }
}

// ---------------------------------------------------------------------------
// MEGA (8-wave, 64-slot, mp-batched): Qe gather-MFMA (K=32) -> edge-attn ->
// ned in LDS -> K1 MFMA (K=256) -> node-attn L1. R8-verified best config.
// (R9's register prefetch of Kn/Q1 spilled to scratch at the allocator's
// 64-VGPR operating point — WRITE_SIZE 25->58MB, slower. Keep in-loop loads.)
__global__ __launch_bounds__(512, 4) void k_mega(
        const u16* __restrict__ ebh, const u16* __restrict__ ebl, // [NMP][E][32]
        const int* __restrict__ eid,                              // [NMP][NSLOT]
        const u16* __restrict__ qeh, const u16* __restrict__ qel, // [NMP][256][32]
        const float* __restrict__ Knb,                            // [NMP][N][256]
        const int* __restrict__ adjAb, const int* __restrict__ adjBb,
        const u16* __restrict__ kth, const u16* __restrict__ ktl, // [NMP][256][256]
        const float* __restrict__ Q1b,                            // [NMP][B][256]
        float* __restrict__ xcat, u16* __restrict__ xhb, u16* __restrict__ xlb) {
    int mp = blockIdx.z;
    const u16* Ah = ebh + (size_t)mp * E_EDGES * E_DIMC;
    const u16* Al = ebl + (size_t)mp * E_EDGES * E_DIMC;
    const int* rows = eid + (size_t)mp * NSLOT;
    const u16* qBh = qeh + (size_t)mp * 8192;
    const u16* qBl = qel + (size_t)mp * 8192;
    const float* Kn = Knb + (size_t)mp * N_NODES * D1;
    const int* adjA = adjAb + (size_t)mp * NSLOT;
    const int* adjB = adjBb + (size_t)mp * NSLOT;
    const u16* kBh = kth + (size_t)mp * 65536;
    const u16* kBl = ktl + (size_t)mp * 65536;
    const float* q = Q1b + (size_t)mp * B_TR * D1;
    float* xrow = xcat + (size_t)mp * B_TR * 2 * D1;
    u16* xh = xhb + (size_t)mp * B_TR * 2 * D1;
    u16* xl = xlb + (size_t)mp * B_TR * 2 * D1;

    __shared__ u16 sh_[64][NPAD];
    __shared__ u16 sl_[64][NPAD];
    int w = threadIdx.x >> 6, lane = threadIdx.x & 63;
    int wr = w & 1, wc = w >> 1;
    int blk = blockIdx.x * 64;
    int rbase = blk + wr * 32;
    int bn = wc * 64;
    int fr = lane & 15, kq = (lane >> 4) * 8;
    int cn = lane & 15, cr = (lane >> 4) * 4;

    // preload adj row offsets for this wave's 8 (i,r) slots
    int raA[2][4], raB[2][4];
    #pragma unroll
    for (int i = 0; i < 2; ++i)
        #pragma unroll
        for (int r = 0; r < 4; ++r) {
            int slot = rbase + i * 16 + cr + r;
            raA[i][r] = adjA[slot] * D1;
            raB[i][r] = adjB[slot] * D1;
        }

    // ---- phase 1: Qe = emb[eid] @ Wqe (K=32, gather), M=32 N=64 ----
    f4v acc[2][4];
    #pragma unroll
    for (int i = 0; i < 2; ++i)
        #pragma unroll
        for (int j = 0; j < 4; ++j) acc[i][j] = f4v{0.f, 0.f, 0.f, 0.f};
    {
        s8v ah[2], al[2], bh[4], bl[4];
        #pragma unroll
        for (int i = 0; i < 2; ++i) {
            size_t ao = (size_t)rows[rbase + i * 16 + fr] * E_DIMC + kq;
            ah[i] = *(const s8v*)(Ah + ao);
            al[i] = *(const s8v*)(Al + ao);
        }
        #pragma unroll
        for (int j = 0; j < 4; ++j) {
            size_t bo = (size_t)(bn + j * 16 + fr) * E_DIMC + kq;
            bh[j] = *(const s8v*)(qBh + bo);
            bl[j] = *(const s8v*)(qBl + bo);
        }
        #pragma unroll
        for (int i = 0; i < 2; ++i)
            #pragma unroll
            for (int j = 0; j < 4; ++j) {
                acc[i][j] = __builtin_amdgcn_mfma_f32_16x16x32_bf16(al[i], bh[j], acc[i][j], 0, 0, 0);
                acc[i][j] = __builtin_amdgcn_mfma_f32_16x16x32_bf16(ah[i], bl[j], acc[i][j], 0, 0, 0);
                acc[i][j] = __builtin_amdgcn_mfma_f32_16x16x32_bf16(ah[i], bh[j], acc[i][j], 0, 0, 0);
            }
    }

    // ---- phase 2: edge attention epilogue -> ned hi/lo into LDS ----
    #pragma unroll
    for (int i = 0; i < 2; ++i) {
        #pragma unroll
        for (int r = 0; r < 4; ++r) {
            int lrow = wr * 32 + i * 16 + cr + r;
            size_t ra = (size_t)raA[i][r];
            size_t rb = (size_t)raB[i][r];
            float kA[4], kB[4];
            float pA = 0.f, pB = 0.f;
            #pragma unroll
            for (int j = 0; j < 4; ++j) {
                int col = bn + j * 16 + cn;
                kA[j] = Kn[ra + col];
                kB[j] = Kn[rb + col];
                pA += acc[i][j][r] * kA[j];
                pB += acc[i][j][r] * kB[j];
            }
            float lA = grp16_sum(pA) * 0.125f;
            float lB = grp16_sum(pB) * 0.125f;
            float m = fmaxf(lA, lB);
            float eA = expf(lA - m), eB = expf(lB - m);
            float inv = 1.f / (eA + eB);
            #pragma unroll
            for (int j = 0; j < 4; ++j) {
                int col = bn + j * 16 + cn;
                float v = eluf(acc[i][j][r] + (eA * kA[j] + eB * kB[j]) * inv);
                u16 hh, ll; splitbf(v, hh, ll);
                sh_[lrow][col] = hh;
                sl_[lrow][col] = ll;
            }
        }
    }
    __syncthreads();

    // ---- phase 3: K1 = ned @ wk1 (K=256, A from LDS), M=32 N=64 ----
    #pragma unroll
    for (int i = 0; i < 2; ++i)
        #pragma unroll
        for (int j = 0; j < 4; ++j) acc[i][j] = f4v{0.f, 0.f, 0.f, 0.f};
    #pragma unroll 2
    for (int k0 = 0; k0 < 256; k0 += 32) {
        s8v ah[2], al[2], bh[4], bl[4];
        #pragma unroll
        for (int i = 0; i < 2; ++i) {
            int lr = wr * 32 + i * 16 + fr;
            ah[i] = *(const s8v*)&sh_[lr][k0 + kq];
            al[i] = *(const s8v*)&sl_[lr][k0 + kq];
        }
        #pragma unroll
        for (int j = 0; j < 4; ++j) {
            size_t bo = (size_t)(bn + j * 16 + fr) * 256 + k0 + kq;
            bh[j] = *(const s8v*)(kBh + bo);
            bl[j] = *(const s8v*)(kBl + bo);
        }
        #pragma unroll
        for (int i = 0; i < 2; ++i)
            #pragma unroll
            for (int j = 0; j < 4; ++j) {
                acc[i][j] = __builtin_amdgcn_mfma_f32_16x16x32_bf16(al[i], bh[j], acc[i][j], 0, 0, 0);
                acc[i][j] = __builtin_amdgcn_mfma_f32_16x16x32_bf16(ah[i], bl[j], acc[i][j], 0, 0, 0);
                acc[i][j] = __builtin_amdgcn_mfma_f32_16x16x32_bf16(ah[i], bh[j], acc[i][j], 0, 0, 0);
            }
    }

    // ---- phase 4: node attention L1 epilogue -> xcat[:,256:512] ----
    int grp = lane >> 4;
    #pragma unroll
    for (int i = 0; i < 2; ++i) {
        int b = (rbase >> 4) + i;
        float qv[4];
        #pragma unroll
        for (int j = 0; j < 4; ++j)
            qv[j] = q[(size_t)b * D1 + bn + j * 16 + cn];
        float lg[4];
        #pragma unroll
        for (int r = 0; r < 4; ++r) {
            float p = 0.f;
            #pragma unroll
            for (int j = 0; j < 4; ++j) p += acc[i][j][r] * qv[j];
            lg[r] = grp16_sum(p) * 0.125f;
        }
        float mx = fmaxf(fmaxf(lg[0], lg[1]), fmaxf(lg[2], lg[3]));
        mx = fmaxf(mx, __shfl_xor(mx, 16, 64));
        mx = fmaxf(mx, __shfl_xor(mx, 32, 64));
        float e[4], s = 0.f;
        #pragma unroll
        for (int r = 0; r < 4; ++r) { e[r] = expf(lg[r] - mx); s += e[r]; }
        s += __shfl_xor(s, 16, 64);
        s += __shfl_xor(s, 32, 64);
        float inv = 1.f / s;
        #pragma unroll
        for (int j = 0; j < 4; ++j) {
            float ag = e[0] * acc[i][j][0] + e[1] * acc[i][j][1]
                     + e[2] * acc[i][j][2] + e[3] * acc[i][j][3];
            ag += __shfl_xor(ag, 16, 64);
            ag += __shfl_xor(ag, 32, 64);
            float v = eluf(qv[j] + ag * inv);
            if (grp == 0) {
                int col = bn + j * 16 + cn;
                xrow[(size_t)b * (2 * D1) + D1 + col] = v;
                u16 hh, ll; splitbf(v, hh, ll);
                xh[(size_t)b * (2 * D1) + D1 + col] = hh;
                xl[(size_t)b * (2 * D1) + D1 + col] = ll;
            }
        }
    }
}

// ---------------------------------------------------------------------------
// slot tables (both mp in one launch)
__global__ void k_slot_setup2(const int* __restrict__ n2e,
                              const int* __restrict__ adj,
                              const int* __restrict__ tid,
                              int* __restrict__ eid,
                              int* __restrict__ adjA,
                              int* __restrict__ adjB) {
    int i = blockIdx.x * blockDim.x + threadIdx.x;
    if (i >= NMP * NSLOT) return;
    int mp = i / NSLOT, sl = i - mp * NSLOT;
    int b = sl >> 4, s = sl & 15;
    int e = n2e[(size_t)mp * N_NODES * S_NE + (size_t)tid[b] * S_NE + s];
    eid[i] = e;
    adjA[i] = adj[(size_t)mp * E_EDGES * 2 + (size_t)e * 2 + 0];
    adjB[i] = adj[(size_t)mp * E_EDGES * 2 + (size_t)e * 2 + 1];
}

// gate finish
template <typename T>
__device__ void gate_fin_body(const float* gmat, const void* vg, float* gate_pre) {
    int row = blockIdx.x;
    int t = threadIdx.x;   // 128
    float v = tanhf(gmat[(size_t)row * PREP + t]) * ldv<T>(vg, t);
    __shared__ float red[128];
    red[t] = v;
    __syncthreads();
    for (int s = 64; s > 0; s >>= 1) { if (t < s) red[t] += red[t + s]; __syncthreads(); }
    if (t == 0) gate_pre[row] = red[0];
}
__global__ void k_gate_fin(const float* gmat, const void* vg, float* gate_pre,
                           const int* flag) {
    if (*flag == 1) gate_fin_body<float>(gmat, vg, gate_pre);
    else            gate_fin_body<bf16 >(gmat, vg, gate_pre);
}

// fallback gate (direct from xcat)
template <typename T>
__device__ void gate_dir_body(const float* xcat, const void* Wg, const void* vg,
                              float* gate_pre) {
    int mb = blockIdx.x;
    int t = threadIdx.x;   // 128
    __shared__ float xr[2 * D1];
    for (int idx = t; idx < 2 * D1; idx += 128) xr[idx] = xcat[(size_t)mb * (2 * D1) + idx];
    __syncthreads();
    float acc = 0.f;
    for (int d = 0; d < 2 * D1; ++d) acc += xr[d] * ldv<T>(Wg, (size_t)d * PREP + t);
    float gp = tanhf(acc) * ldv<T>(vg, t);
    __shared__ float red[128];
    red[t] = gp;
    __syncthreads();
    for (int s = 64; s > 0; s >>= 1) { if (t < s) red[t] += red[t + s]; __syncthreads(); }
    if (t == 0) gate_pre[mb] = red[0];
}
__global__ void k_gate_direct(const float* xcat, const void* Wg, const void* vg,
                              float* gate_pre, const int* flag) {
    if (*flag == 1) gate_dir_body<float>(xcat, Wg, vg, gate_pre);
    else            gate_dir_body<bf16 >(xcat, Wg, vg, gate_pre);
}

// final
template <typename T>
__device__ void final_body(const float* xcat, const float* gate_pre,
                           const void* Wfc, const void* bfc, void* out) {
    int b = blockIdx.x;
    int t = threadIdx.x;  // 64
    float g0 = gate_pre[b], g1 = gate_pre[B_TR + b];
    float mx = fmaxf(g0, g1);
    float e0 = expf(g0 - mx), e1 = expf(g1 - mx);
    float inv = 1.f / (e0 + e1);
    float w0 = e0 * inv, w1 = e1 * inv;
    __shared__ float pooled[2 * D1];
    for (int d = t; d < 2 * D1; d += 64)
        pooled[d] = w0 * xcat[(size_t)b * (2 * D1) + d]
                  + w1 * xcat[(size_t)(B_TR + b) * (2 * D1) + d];
    __syncthreads();
    if (t < NCLS) {
        float acc = ldv<T>(bfc, t);
        for (int d = 0; d < 2 * D1; ++d) acc += pooled[d] * ldv<T>(Wfc, (size_t)d * NCLS + t);
        stv<T>(out, (size_t)b * NCLS + t, acc);
    }
    if (t == 8) stv<T>(out, (size_t)B_TR * NCLS + b, w0);
    if (t == 9) stv<T>(out, (size_t)B_TR * NCLS + B_TR + b, w1);
}
__global__ void k_final(const float* xcat, const float* gate_pre,
                        const void* Wfc, const void* bfc, void* out,
                        const int* flag) {
    if (*flag == 1) final_body<float>(xcat, gate_pre, Wfc, bfc, out);
    else            final_body<bf16 >(xcat, gate_pre, Wfc, bfc, out);
}

// ---------------------------------------------------------------------------
// Fallback kernels (R4-verified fused path)
template <typename T>
__global__ void k_prep_nodes(const void* __restrict__ feats,
                             const void* __restrict__ W,
                             float* __restrict__ out,
                             const int* __restrict__ flag) {
    if (!active<T>(flag)) return;
    int g = blockIdx.x * blockDim.x + threadIdx.x;
    if (g >= N_NODES * 32) return;
    int n = g >> 5, pg = g & 31;
    float4 acc; ZERO4(acc);
    #pragma unroll 8
    for (int d = 0; d < D_FEAT; ++d) {
        float f = ldv<T>(feats, (size_t)n * D_FEAT + d);
        float4 w4 = ld4<T>(W, (size_t)d * PREP + pg * 4);
        FMA4C(acc, f, w4);
    }
    *(float4*)(out + (size_t)n * PREP + pg * 4) = acc;
}

template <typename T>
__global__ __launch_bounds__(256) void k_fused(
        const void* __restrict__ feats,
        const void* __restrict__ edge_emb_mp,
        const void* __restrict__ W_prep0,
        const void* __restrict__ epw_mp,
        const void* __restrict__ ewq,
        const void* __restrict__ ewk,
        const void* __restrict__ nwq0,
        const void* __restrict__ nwk0,
        const void* __restrict__ nwq1,
        const void* __restrict__ nwk1,
        const int*  __restrict__ n2e_mp,
        const int*  __restrict__ adj_mp,
        const int*  __restrict__ tid,
        const float* __restrict__ all_feats0,
        float* __restrict__ xcat_mp,
        const int* __restrict__ flag) {
    if (!active<T>(flag)) return;
    int b = blockIdx.x;
    int t = threadIdx.x;
    int h = t >> 6;
    int lane = t & 63;
    int mg = lane & 3, og = lane >> 2;

    __shared__ int   s_eid[S_NE];
    __shared__ int   s_nrow[2 * S_NE];
    __shared__ __align__(16) float s_emb[S_NE * E_DIMC];
    __shared__ __align__(16) float s_f[D_FEAT];
    __shared__ __align__(16) float s_q0[PREP];
    __shared__ __align__(16) float s_eprep[S_NE * LDA0];
    __shared__ __align__(16) float s_xn_pool[2 * S_NE * LDA0];
    __shared__ __align__(16) float s_out0[D1];
    float* s_nedge = s_xn_pool;

    int tid_b = tid[b];
    if (t < S_NE)   s_eid[t] = n2e_mp[(size_t)tid_b * S_NE + t];
    if (t < D_FEAT) s_f[t] = ldv<T>(feats, (size_t)tid_b * D_FEAT + t);
    __syncthreads();

    if (t < 2 * S_NE) s_nrow[t] = adj_mp[(size_t)s_eid[t >> 1] * 2 + (t & 1)];
    {
        int j = t, s = j >> 5, d = j & 31;
        s_emb[j] = ldv<T>(edge_emb_mp, (size_t)s_eid[s] * E_DIMC + d);
        j = t + 256; s = j >> 5; d = j & 31;
        s_emb[j] = ldv<T>(edge_emb_mp, (size_t)s_eid[s] * E_DIMC + d);
    }
    if (t < PREP) {
        float a = 0.f;
        #pragma unroll
        for (int d = 0; d < D_FEAT; ++d) a += s_f[d] * ldv<T>(W_prep0, d * PREP + t);
        s_q0[t] = a;
    }
    __syncthreads();

    #pragma unroll
    for (int k = 0; k < 4; ++k) {
        int j = t + 256 * k;
        int r = j >> 5, dc = j & 31;
        float4 v = *(const float4*)(all_feats0 + (size_t)s_nrow[r] * PREP + dc * 4);
        *(float4*)&s_xn_pool[r * LDA0 + dc * 4] = v;
    }
    {
        int s = t >> 4, pg = t & 15;
        float4 a0, a1; ZERO4(a0); ZERO4(a1);
        #pragma unroll
        for (int d = 0; d < E_DIMC; ++d) {
            float e = s_emb[s * E_DIMC + d];
            float4 w0 = ld4<T>(epw_mp, (size_t)d * PREP + pg * 8);
            float4 w1 = ld4<T>(epw_mp, (size_t)d * PREP + pg * 8 + 4);
            FMA4C(a0, e, w0); FMA4C(a1, e, w1);
        }
        *(float4*)&s_eprep[s * LDA0 + pg * 8]     = a0;
        *(float4*)&s_eprep[s * LDA0 + pg * 8 + 4] = a1;
    }
    __syncthreads();

    float4 aq[4], ak[8];
    #pragma unroll
    for (int i = 0; i < 4; ++i) ZERO4(aq[i]);
    #pragma unroll
    for (int i = 0; i < 8; ++i) ZERO4(ak[i]);
    {
        size_t wb = (size_t)h * PREP * O_DIM + og * 4;
        for (int kk = 0; kk < PREP; kk += 4) {
            float4 bq[4], bk[4];
            #pragma unroll
            for (int j = 0; j < 4; ++j) {
                bq[j] = ld4<T>(ewq, wb + (size_t)(kk + j) * O_DIM);
                bk[j] = ld4<T>(ewk, wb + (size_t)(kk + j) * O_DIM);
            }
            #pragma unroll
            for (int i = 0; i < 4; ++i) {
                float4 a = *(const float4*)&s_eprep[(mg + 4 * i) * LDA0 + kk];
                FMA4C(aq[i], a.x, bq[0]); FMA4C(aq[i], a.y, bq[1]);
                FMA4C(aq[i], a.z, bq[2]); FMA4C(aq[i], a.w, bq[3]);
            }
            #pragma unroll
            for (int i = 0; i < 8; ++i) {
                int r = 2 * mg + (i & 1) + 8 * (i >> 1);
                float4 a = *(const float4*)&s_xn_pool[r * LDA0 + kk];
                FMA4C(ak[i], a.x, bk[0]); FMA4C(ak[i], a.y, bk[1]);
                FMA4C(ak[i], a.z, bk[2]); FMA4C(ak[i], a.w, bk[3]);
            }
        }
    }
    __syncthreads();

    #pragma unroll
    for (int j = 0; j < 4; ++j) {
        int s = mg + 4 * j;
        float4 q = aq[j], kA = ak[2 * j], kB = ak[2 * j + 1];
        float lA = og_sum(q.x * kA.x + q.y * kA.y + q.z * kA.z + q.w * kA.w) * 0.125f;
        float lB = og_sum(q.x * kB.x + q.y * kB.y + q.z * kB.z + q.w * kB.w) * 0.125f;
        float m = fmaxf(lA, lB);
        float eA = expf(lA - m), eB = expf(lB - m);
        float inv = 1.f / (eA + eB);
        float4 v;
        v.x = q.x + (eA * kA.x + eB * kB.x) * inv;
        v.y = q.y + (eA * kA.y + eB * kB.y) * inv;
        v.z = q.z + (eA * kA.z + eB * kB.z) * inv;
        v.w = q.w + (eA * kA.w + eB * kB.w) * inv;
        *(float4*)&s_nedge[s * LDA1 + h * O_DIM + og * 4] = elu4(v);
    }

    float4 zq; ZERO4(zq);
    float4 zk[4];
    #pragma unroll
    for (int i = 0; i < 4; ++i) ZERO4(zk[i]);
    {
        size_t wb = (size_t)h * PREP * O_DIM + og * 4;
        for (int kk = 0; kk < PREP; kk += 4) {
            float4 q4 = *(const float4*)&s_q0[kk];
            float4 bq[4], bk[4];
            #pragma unroll
            for (int j = 0; j < 4; ++j) {
                bq[j] = ld4<T>(nwq0, wb + (size_t)(kk + j) * O_DIM);
                bk[j] = ld4<T>(nwk0, wb + (size_t)(kk + j) * O_DIM);
            }
            FMA4C(zq, q4.x, bq[0]); FMA4C(zq, q4.y, bq[1]);
            FMA4C(zq, q4.z, bq[2]); FMA4C(zq, q4.w, bq[3]);
            #pragma unroll
            for (int i = 0; i < 4; ++i) {
                float4 a = *(const float4*)&s_eprep[(mg + 4 * i) * LDA0 + kk];
                FMA4C(zk[i], a.x, bk[0]); FMA4C(zk[i], a.y, bk[1]);
                FMA4C(zk[i], a.z, bk[2]); FMA4C(zk[i], a.w, bk[3]);
            }
        }
    }
    {
        float lg[4];
        #pragma unroll
        for (int j = 0; j < 4; ++j)
            lg[j] = og_sum(zq.x * zk[j].x + zq.y * zk[j].y +
                           zq.z * zk[j].z + zq.w * zk[j].w) * 0.125f;
        float mx = fmaxf(fmaxf(lg[0], lg[1]), fmaxf(lg[2], lg[3]));
        mx = mg_max(mx);
        float ea[4], ssum = 0.f;
        #pragma unroll
        for (int j = 0; j < 4; ++j) { ea[j] = expf(lg[j] - mx); ssum += ea[j]; }
        ssum = mg_sum(ssum);
        float inv = 1.f / ssum;
        float4 part; ZERO4(part);
        #pragma unroll
        for (int j = 0; j < 4; ++j) FMA4C(part, ea[j], zk[j]);
        part.x = mg_sum(part.x); part.y = mg_sum(part.y);
        part.z = mg_sum(part.z); part.w = mg_sum(part.w);
        float4 v;
        v.x = zq.x + part.x * inv; v.y = zq.y + part.y * inv;
        v.z = zq.z + part.z * inv; v.w = zq.w + part.w * inv;
        v = elu4(v);
        if (mg == 0) {
            *(float4*)&s_out0[h * O_DIM + og * 4] = v;
            *(float4*)(xcat_mp + (size_t)b * (2 * D1) + h * O_DIM + og * 4) = v;
        }
    }
    __syncthreads();

    ZERO4(zq);
    #pragma unroll
    for (int i = 0; i < 4; ++i) ZERO4(zk[i]);
    {
        size_t wb = (size_t)h * D1 * O_DIM + og * 4;
        for (int kk = 0; kk < D1; kk += 4) {
            float4 q4 = *(const float4*)&s_out0[kk];
            float4 bq[4], bk[4];
            #pragma unroll
            for (int j = 0; j < 4; ++j) {
                bq[j] = ld4<T>(nwq1, wb + (size_t)(kk + j) * O_DIM);
                bk[j] = ld4<T>(nwk1, wb + (size_t)(kk + j) * O_DIM);
            }
            FMA4C(zq, q4.x, bq[0]); FMA4C(zq, q4.y, bq[1]);
            FMA4C(zq, q4.z, bq[2]); FMA4C(zq, q4.w, bq[3]);
            #pragma unroll
            for (int i = 0; i < 4; ++i) {
                float4 a = *(const float4*)&s_nedge[(mg + 4 * i) * LDA1 + kk];
                FMA4C(zk[i], a.x, bk[0]); FMA4C(zk[i], a.y, bk[1]);
                FMA4C(zk[i], a.z, bk[2]); FMA4C(zk[i], a.w, bk[3]);
            }
        }
    }
    {
        float lg[4];
        #pragma unroll
        for (int j = 0; j < 4; ++j)
            lg[j] = og_sum(zq.x * zk[j].x + zq.y * zk[j].y +
                           zq.z * zk[j].z + zq.w * zk[j].w) * 0.125f;
        float mx = fmaxf(fmaxf(lg[0], lg[1]), fmaxf(lg[2], lg[3]));
        mx = mg_max(mx);
        float ea[4], ssum = 0.f;
        #pragma unroll
        for (int j = 0; j < 4; ++j) { ea[j] = expf(lg[j] - mx); ssum += ea[j]; }
        ssum = mg_sum(ssum);
        float inv = 1.f / ssum;
        float4 part; ZERO4(part);
        #pragma unroll
        for (int j = 0; j < 4; ++j) FMA4C(part, ea[j], zk[j]);
        part.x = mg_sum(part.x); part.y = mg_sum(part.y);
        part.z = mg_sum(part.z); part.w = mg_sum(part.w);
        float4 v;
        v.x = zq.x + part.x * inv; v.y = zq.y + part.y * inv;
        v.z = zq.z + part.z * inv; v.w = zq.w + part.w * inv;
        v = elu4(v);
        if (mg == 0)
            *(float4*)(xcat_mp + (size_t)b * (2 * D1) + D1 + h * O_DIM + og * 4) = v;
    }
}

// ---------------------------------------------------------------------------
extern "C" void kernel_launch(void* const* d_in, const int* in_sizes, int n_in,
                              void* d_out, int out_size, void* d_ws, size_t ws_size,
                              hipStream_t stream) {
    const void* feats       = d_in[0];
    const void* edge_emb    = d_in[1];
    const void* W_prep0     = d_in[2];
    const void* W_prep1     = d_in[3];
    const void* edge_prep_w = d_in[4];
    const void* e_wq0       = d_in[5];
    const void* e_wk0       = d_in[6];
    const void* n_wq0       = d_in[9];
    const void* n_wk0       = d_in[10];
    const void* n_wq1       = d_in[11];
    const void* n_wk1       = d_in[12];
    const void* Wg          = d_in[13];
    const void* vg          = d_in[14];
    const void* Wfc         = d_in[15];
    const void* bfc         = d_in[16];
    const int*  n2e         = (const int*)d_in[17];
    const int*  adj         = (const int*)d_in[18];
    const int*  tid         = (const int*)d_in[19];

    float* ws   = (float*)d_ws;
    int*   flag = (int*)ws;            // ws[0]
    float* base = ws + 4;
    size_t avail = (ws_size >= 16) ? (ws_size - 16) / 4 : 0;   // floats

    k_detect<<<1, 64, 0, stream>>>((const unsigned*)feats, flag);

    // ---- main-path fixed layout (float units; u16 buffers = n/2 floats) ----
    size_t off = 0;
    auto alloc = [&](size_t n) { size_t o = off; off += (n + 3) & ~(size_t)3; return o; };
    size_t o_xcat = alloc((size_t)NMP * B_TR * 2 * D1);       // 4.19M
    size_t o_gmat = alloc((size_t)NMP * B_TR * PREP);         // 1.05M
    size_t o_gpre = alloc(NMP * B_TR);
    size_t o_wkn  = alloc(NMP * 64 * D1);
    size_t o_wq0  = alloc(NMP * 64 * D1);
    size_t o_qeh  = alloc(NMP * 256 * 32 / 2);                // u16 planes
    size_t o_qel  = alloc(NMP * 256 * 32 / 2);
    size_t o_k0h  = alloc(NMP * 256 * 32 / 2);
    size_t o_k0l  = alloc(NMP * 256 * 32 / 2);
    size_t o_ebh  = alloc((size_t)NMP * E_EDGES * E_DIMC / 2); // 5.12M
    size_t o_ebl  = alloc((size_t)NMP * E_EDGES * E_DIMC / 2); // 5.12M
    size_t o_Kn   = alloc((size_t)NMP * N_NODES * D1);        // 10.24M
    size_t o_q0   = alloc((size_t)NMP * B_TR * D1);
    size_t o_Q1   = alloc((size_t)NMP * B_TR * D1);
    size_t o_eid  = alloc((size_t)NMP * NSLOT);
    size_t o_adjA = alloc((size_t)NMP * NSLOT);
    size_t o_adjB = alloc((size_t)NMP * NSLOT);
    size_t o_o0h  = alloc((size_t)NMP * B_TR * D1 / 2);
    size_t o_o0l  = alloc((size_t)NMP * B_TR * D1 / 2);
    size_t o_xh   = alloc((size_t)NMP * B_TR * D1);           // 512 u16/row
    size_t o_xl   = alloc((size_t)NMP * B_TR * D1);
    size_t o_wk1h = alloc((size_t)NMP * 32768);               // 256x256 u16
    size_t o_wk1l = alloc((size_t)NMP * 32768);
    size_t o_wq1h = alloc((size_t)NMP * 32768);
    size_t o_wq1l = alloc((size_t)NMP * 32768);
    size_t o_wgh  = alloc(32768);                             // 128x512 u16
    size_t o_wgl  = alloc(32768);
    size_t fixed = off;

    int CH = (fixed <= avail) ? B_TR : 0;

    if (CH > 0) {
        float* xcat = base + o_xcat;
        float* gmat = base + o_gmat;
        float* gpre = base + o_gpre;
        float* wkn  = base + o_wkn;
        float* wq0  = base + o_wq0;
        u16*   qeh  = (u16*)(base + o_qeh);
        u16*   qel  = (u16*)(base + o_qel);
        u16*   k0h  = (u16*)(base + o_k0h);
        u16*   k0l  = (u16*)(base + o_k0l);
        u16*   ebh  = (u16*)(base + o_ebh);
        u16*   ebl  = (u16*)(base + o_ebl);
        float* Kn   = base + o_Kn;
        float* q0   = base + o_q0;
        float* Q1   = base + o_Q1;
        int*   eid  = (int*)(base + o_eid);
        int*   adjA = (int*)(base + o_adjA);
        int*   adjB = (int*)(base + o_adjB);
        u16*   o0h  = (u16*)(base + o_o0h);
        u16*   o0l  = (u16*)(base + o_o0l);
        u16*   xh   = (u16*)(base + o_xh);
        u16*   xl   = (u16*)(base + o_xl);
        u16*   wk1h = (u16*)(base + o_wk1h);
        u16*   wk1l = (u16*)(base + o_wk1l);
        u16*   wq1h = (u16*)(base + o_wq1h);
        u16*   wq1l = (u16*)(base + o_wq1l);
        u16*   wgh  = (u16*)(base + o_wgh);
        u16*   wgl  = (u16*)(base + o_wgl);

        // ---- preprocessing (mp-batched already) ----
        k_precomb2<<<384, 256, 0, stream>>>(edge_prep_w, e_wq0, n_wk0, W_prep1,
                                            e_wk0, W_prep0, n_wq0,
                                            wkn, wq0, qeh, qel, k0h, k0l, flag);
        k_embsplit<<<(NMP * E_EDGES * E_DIMC + 255) / 256, 256, 0, stream>>>(
            edge_emb, ebh, ebl, flag);
        k_wt1<<<1024, 256, 0, stream>>>(n_wk1, n_wq1, wk1h, wk1l, wq1h, wq1l, flag);
        k_wgt<<<256, 256, 0, stream>>>(Wg, wgh, wgl, flag);
        k_slot_setup2<<<(NMP * NSLOT + 255) / 256, 256, 0, stream>>>(
            n2e, adj, tid, eid, adjA, adjB);

        // ---- main chain, one launch per stage (blockIdx.z = mp) ----
        // Kn[mp] = feats @ Wkn[mp]   [N,256], K=64
        k_gemm_rf<<<dim3((N_NODES + 63) / 64, 4, NMP), 256, 0, stream>>>(
            feats, 0, nullptr, D_FEAT,
            wkn, (size_t)64 * D1, 64, D1,
            Kn, (size_t)N_NODES * D1, D1, N_NODES, D_FEAT, flag);
        // q0[mp] = feats[tid] @ Wq0[mp]   [B,256], K=64
        k_gemm_rf<<<dim3(B_TR / 64, 4, NMP), 256, 0, stream>>>(
            feats, 0, tid, D_FEAT,
            wq0, (size_t)64 * D1, 64, D1,
            q0, (size_t)B_TR * D1, D1, B_TR, D_FEAT, flag);
        // L0: K0 gather-MFMA + node attn -> o0 planes + xcat[:,0:256]
        k_nattn0<<<dim3(NSLOT / 128, 2, NMP), 256, 0, stream>>>(
            ebh, ebl, eid, k0h, k0l, q0, o0h, o0l, xcat, xh, xl);
        // Q1[mp] = o0[mp] @ nwq1[mp]  (MFMA, K=256)
        k_q1<<<dim3(B_TR / 128, 2, NMP), 256, 0, stream>>>(
            o0h, o0l, wq1h, wq1l, Q1);
        // MEGA: Qe + edge attn + K1 + node attn L1 (ned in LDS)
        k_mega<<<dim3(NSLOT / 64, 1, NMP), 512, 0, stream>>>(
            ebh, ebl, eid, qeh, qel, Kn, adjA, adjB,
            wk1h, wk1l, Q1, xcat, xh, xl);

        // gate: gmat = xcat @ Wg  [8192,128], K=512 (MFMA from x planes)
        k_mfma<512><<<dim3(NMP * B_TR / 128, 1), 256, 0, stream>>>(
            xh, xl, wgh, wgl, gmat, PREP);
        k_gate_fin<<<NMP * B_TR, 128, 0, stream>>>(gmat, vg, gpre, flag);
        k_final<<<B_TR, 64, 0, stream>>>(xcat, gpre, Wfc, bfc, d_out, flag);
    } else {
        // ------------- fused fallback (R4) -------------
        size_t f_off = 0;
        auto falloc = [&](size_t n) { size_t o = f_off; f_off += (n + 3) & ~(size_t)3; return o; };
        float* af0  = base + falloc((size_t)N_NODES * PREP);
        float* xcat = base + falloc((size_t)NMP * B_TR * 2 * D1);
        float* gpre = base + falloc(NMP * B_TR);

        k_prep_nodes<float><<<(N_NODES * 32 + 255) / 256, 256, 0, stream>>>(
            feats, W_prep1, af0, flag);
        k_prep_nodes<bf16><<<(N_NODES * 32 + 255) / 256, 256, 0, stream>>>(
            feats, W_prep1, af0, flag);

        for (int mp = 0; mp < NMP; ++mp) {
            #define FUSED_ARGS(esz)                                                   \
                feats,                                                                \
                (const char*)edge_emb + (esz) * (size_t)mp * E_EDGES * E_DIMC,        \
                W_prep0,                                                              \
                (const char*)edge_prep_w + (esz) * (size_t)mp * E_DIMC * PREP,        \
                (const char*)e_wq0 + (esz) * (size_t)mp * H_HEADS * PREP * O_DIM,     \
                (const char*)e_wk0 + (esz) * (size_t)mp * H_HEADS * PREP * O_DIM,     \
                (const char*)n_wq0 + (esz) * (size_t)mp * H_HEADS * PREP * O_DIM,     \
                (const char*)n_wk0 + (esz) * (size_t)mp * H_HEADS * PREP * O_DIM,     \
                (const char*)n_wq1 + (esz) * (size_t)mp * H_HEADS * D1 * O_DIM,       \
                (const char*)n_wk1 + (esz) * (size_t)mp * H_HEADS * D1 * O_DIM,       \
                n2e + (size_t)mp * N_NODES * S_NE,                                    \
                adj + (size_t)mp * E_EDGES * 2,                                       \
                tid, af0, xcat + (size_t)mp * B_TR * 2 * D1, flag
            k_fused<float><<<B_TR, 256, 0, stream>>>(FUSED_ARGS(4));
            k_fused<bf16><<<B_TR, 256, 0, stream>>>(FUSED_ARGS(2));
            #undef FUSED_ARGS
        }
        k_gate_direct<<<NMP * B_TR, 128, 0, stream>>>(xcat, Wg, vg, gpre, flag);
        k_final<<<B_TR, 64, 0, stream>>>(xcat, gpre, Wfc, bfc, d_out, flag);
    }
}